// Round 12
// baseline (1690.916 us; speedup 1.0000x reference)
//
#include <hip/hip_runtime.h>
#include <math.h>

// ---------------------------------------------------------------------------
// TopoPoolNet: GCN(128->64) -> GCN(64->64) -> sigmoid score gate ->
//              per-graph max||mean pool -> MLP(128->64->2)
//
// Round-11: chunk-phased aggregation. R9 proved lockstep chunk walking cuts
// FETCH (361->241MB); R10 proved sorted-order-without-sync does NOT. Now:
// persistent-ish waves (32 nodes each, 8xfloat4 register acc), loop over 2MB
// source chunks with a grid-wide BOUNDED-SPIN barrier between chunks
// (performance-only: no data dependency, bounded spin -> deadlock-free).
// All 782 blocks co-resident (0 LDS, <=128 VGPR, 4 blocks/CU).
// ---------------------------------------------------------------------------

#define TPN_BLK 256
#define P1_EPT  16                   // edges per thread in bin pass
#define P1_CHUNK (TPN_BLK * P1_EPT)  // 4096 edges per block
#define NB_MAX  512
#define BCAP    12288                // per-bin capacity (mean ~8184)
#define CSH     13                   // source chunk = 8192 nodes = 2 MB
#define NKEY    4096                 // 256 local nodes x 16 chunks

// ---- pass 1: block-level counting sort by bin (col>>8), coalesced out -----
__global__ __launch_bounds__(256)
void tpn_bin(const int* __restrict__ ei, const float* __restrict__ ew,
             int* __restrict__ binCur, uint2* __restrict__ binned,
             int E, int NB) {
    __shared__ uint2          sbuf[P1_CHUNK];      // 32 KB
    __shared__ unsigned short sbin[P1_CHUNK];      // 8 KB
    __shared__ int hist[NB_MAX];
    __shared__ int loff[NB_MAX];
    __shared__ int lrank[NB_MAX];
    __shared__ int gbase[NB_MAX];
    __shared__ int ssc[256];

    int tid = threadIdx.x;
    for (int b = tid; b < NB_MAX; b += 256) { hist[b] = 0; lrank[b] = 0; }
    __syncthreads();

    int base = blockIdx.x * P1_CHUNK;
    uint2 ed[P1_EPT];
    int   bn[P1_EPT];
    #pragma unroll
    for (int j = 0; j < P1_EPT; ++j) {
        int e = base + tid + j * 256;
        bn[j] = -1;
        if (e < E) {
            int r = ei[e], c = ei[E + e];
            bn[j] = c >> 8;
            ed[j] = make_uint2((unsigned)r | ((unsigned)(c & 255) << 17),
                               __float_as_uint(ew[e]));
            atomicAdd(&hist[bn[j]], 1);
        }
    }
    __syncthreads();
    // exclusive scan of hist[0..NB_MAX) -> loff (thread t owns bins 2t, 2t+1)
    {
        int b0 = 2 * tid, b1 = 2 * tid + 1;
        int h0 = hist[b0], h1 = hist[b1];
        int s = h0 + h1;
        ssc[tid] = s;
        __syncthreads();
        for (int st = 1; st < 256; st <<= 1) {
            int v = (tid >= st) ? ssc[tid - st] : 0;
            __syncthreads();
            ssc[tid] += v;
            __syncthreads();
        }
        int pre = ssc[tid] - s;
        loff[b0] = pre;
        loff[b1] = pre + h0;
    }
    __syncthreads();
    for (int b = tid; b < NB; b += 256) {
        int h = hist[b];
        if (h > 0) gbase[b] = atomicAdd(&binCur[b], h);
    }
    #pragma unroll
    for (int j = 0; j < P1_EPT; ++j) {
        if (bn[j] >= 0) {
            int p = loff[bn[j]] + atomicAdd(&lrank[bn[j]], 1);
            sbuf[p] = ed[j];
            sbin[p] = (unsigned short)bn[j];
        }
    }
    __syncthreads();
    int m = min(E - base, P1_CHUNK);
    for (int i = tid; i < m; i += 256) {
        uint2 u = sbuf[i];
        int b = sbin[i];
        int dst = gbase[b] + (i - loff[b]);
        if (dst < BCAP) binned[(size_t)b * BCAP + dst] = u;
    }
}

// ---- exclusive scan of bin counts (single block) ---------------------------
__global__ void tpn_binscan(const int* __restrict__ binCur, int* __restrict__ binOff,
                            int NB) {
    __shared__ int sh[NB_MAX];
    int t = threadIdx.x;
    int v = (t < NB) ? min(binCur[t], BCAP) : 0;
    sh[t] = v;
    __syncthreads();
    for (int st = 1; st < NB_MAX; st <<= 1) {
        int u = (t >= st) ? sh[t - st] : 0;
        __syncthreads();
        sh[t] += u;
        __syncthreads();
    }
    if (t < NB) binOff[t] = sh[t] - v;
}

// ---- pass 2: per-bin (node, source-chunk) counting sort + dis + offcm ------
// key = (local_node << 4) | chunk ; offcm[c][node] = chunk-major offsets.
__global__ __launch_bounds__(256)
void tpn_build(const uint2* __restrict__ binned, const int* __restrict__ binCur,
               const int* __restrict__ binOff, uint2* __restrict__ packed,
               int* __restrict__ offcm, float* __restrict__ dis,
               int N, int Ntot) {
    __shared__ int   kcnt[NKEY];    // 16 KB
    __shared__ int   koff[NKEY];    // 16 KB
    __shared__ int   krank[NKEY];   // 16 KB
    __shared__ float ldeg[256];
    __shared__ int   ssc[256];
    int b = blockIdx.x, tid = threadIdx.x;
    int m = min(binCur[b], BCAP);
    const uint2* src = binned + (size_t)b * BCAP;
    for (int i = tid; i < NKEY; i += 256) { kcnt[i] = 0; krank[i] = 0; }
    ldeg[tid] = 0.0f;
    __syncthreads();
    for (int i = tid; i < m; i += 256) {
        uint2 u = src[i];
        int ln = u.x >> 17;
        int ch = (u.x & 0x1FFFF) >> CSH;
        atomicAdd(&kcnt[(ln << 4) | ch], 1);
        atomicAdd(&ldeg[ln], __uint_as_float(u.y));
    }
    __syncthreads();
    // exclusive scan of kcnt[0..4096): thread t owns keys [16t, 16t+16)
    {
        int base16 = tid << 4;
        int loc[16]; int s = 0;
        #pragma unroll
        for (int i = 0; i < 16; ++i) { loc[i] = s; s += kcnt[base16 + i]; }
        ssc[tid] = s;
        __syncthreads();
        for (int st = 1; st < 256; st <<= 1) {
            int v = (tid >= st) ? ssc[tid - st] : 0;
            __syncthreads();
            ssc[tid] += v;
            __syncthreads();
        }
        int pre = ssc[tid] - s;
        #pragma unroll
        for (int i = 0; i < 16; ++i) koff[base16 + i] = pre + loc[i];
    }
    __syncthreads();
    {
        int node = (b << 8) + tid;
        if (node < N) {
            float s = ldeg[tid];
            dis[node] = (s > 0.0f) ? rsqrtf(fmaxf(s, 1e-12f)) : 0.0f;
        }
    }
    int gb = binOff[b];
    // chunk-major offset table: offcm[ch*Ntot + node] = gb + koff[(ln<<4)|ch]
    for (int k = tid; k < NKEY; k += 256) {
        int ln = k >> 4, ch = k & 15;
        offcm[(size_t)ch * Ntot + (b << 8) + ln] = gb + koff[k];
    }
    for (int i = tid; i < m; i += 256) {
        uint2 u = src[i];
        int ln = u.x >> 17;
        int ch = (u.x & 0x1FFFF) >> CSH;
        int k = (ln << 4) | ch;
        int rk = atomicAdd(&krank[k], 1);
        packed[gb + koff[k] + rk] = make_uint2(u.x & 0x1FFFF, u.y);
    }
}

// ---- tiled GEMM: Y[n,f] = dis[n] * sum_k X[n,k]*W[k,f]; 64x64 tile ---------
__global__ __launch_bounds__(256, 4)
void tpn_gemm_t(const float* __restrict__ X, const float* __restrict__ W,
                const float* __restrict__ dis, float* __restrict__ Y,
                int N, int K) {
    __shared__ float sX[64][68];
    __shared__ float sW[64][64];
    const int t  = threadIdx.x;
    const int r  = t >> 4;
    const int cc = t & 15;
    const int fg = t & 15;
    const int ng = t >> 4;
    const int nb = blockIdx.x * 64;

    float acc[4][4] = {{0.f}};

    for (int kc = 0; kc < K; kc += 64) {
        __syncthreads();
        #pragma unroll
        for (int p = 0; p < 4; ++p) {
            int n = nb + r + p * 16;
            int ns = (n < N) ? n : (N - 1);
            float4 v = *reinterpret_cast<const float4*>(X + (size_t)ns * K + kc + 4 * cc);
            *reinterpret_cast<float4*>(&sX[r + p * 16][4 * cc]) = v;
        }
        #pragma unroll
        for (int p = 0; p < 4; ++p) {
            int k = kc + r + p * 16;
            float4 v = *reinterpret_cast<const float4*>(W + (size_t)k * 64 + 4 * cc);
            *reinterpret_cast<float4*>(&sW[r + p * 16][4 * cc]) = v;
        }
        __syncthreads();
        #pragma unroll 4
        for (int k = 0; k < 64; ++k) {
            float4 wv = *reinterpret_cast<const float4*>(&sW[k][4 * fg]);
            float x0 = sX[4 * ng + 0][k];
            float x1 = sX[4 * ng + 1][k];
            float x2 = sX[4 * ng + 2][k];
            float x3 = sX[4 * ng + 3][k];
            acc[0][0] = fmaf(x0, wv.x, acc[0][0]);
            acc[0][1] = fmaf(x0, wv.y, acc[0][1]);
            acc[0][2] = fmaf(x0, wv.z, acc[0][2]);
            acc[0][3] = fmaf(x0, wv.w, acc[0][3]);
            acc[1][0] = fmaf(x1, wv.x, acc[1][0]);
            acc[1][1] = fmaf(x1, wv.y, acc[1][1]);
            acc[1][2] = fmaf(x1, wv.z, acc[1][2]);
            acc[1][3] = fmaf(x1, wv.w, acc[1][3]);
            acc[2][0] = fmaf(x2, wv.x, acc[2][0]);
            acc[2][1] = fmaf(x2, wv.y, acc[2][1]);
            acc[2][2] = fmaf(x2, wv.z, acc[2][2]);
            acc[2][3] = fmaf(x2, wv.w, acc[2][3]);
            acc[3][0] = fmaf(x3, wv.x, acc[3][0]);
            acc[3][1] = fmaf(x3, wv.y, acc[3][1]);
            acc[3][2] = fmaf(x3, wv.z, acc[3][2]);
            acc[3][3] = fmaf(x3, wv.w, acc[3][3]);
        }
    }
    #pragma unroll
    for (int i = 0; i < 4; ++i) {
        int n = nb + 4 * ng + i;
        if (n < N) {
            float d = dis[n];
            float4 v = make_float4(acc[i][0] * d, acc[i][1] * d,
                                   acc[i][2] * d, acc[i][3] * d);
            *reinterpret_cast<float4*>(Y + (size_t)n * 64 + 4 * fg) = v;
        }
    }
}

// ---- chunk-phased aggregate: wave owns 32 nodes, 4 groups x 4 nodes -------
// Grid-wide soft barrier between 2MB source chunks (performance-only,
// bounded spin -> deadlock-free even without co-residency).
template <bool FUSE_SCORE>
__global__ __launch_bounds__(256, 4)
void tpn_aggc(const uint2* __restrict__ packed, const int* __restrict__ offcm,
              const float* __restrict__ dis, const float* __restrict__ Hin,
              const float* __restrict__ bias, const float* __restrict__ pw,
              const float* __restrict__ pb, float* __restrict__ Hout,
              int N, int Ntot, int NCH, int* __restrict__ bar, int nblk) {
    const int tid  = threadIdx.x;
    const int wid  = blockIdx.x * 4 + (tid >> 6);
    const int lane = tid & 63;
    const int l32  = lane & 31;
    const int g    = lane >> 4;          // group 0..3 (node i%4 == g)
    const int fb   = (lane & 15) * 4;    // feature base
    const int nodeBase = wid * 32;
    const float* hp = Hin + fb;

    float4 a[8];
    #pragma unroll
    for (int t = 0; t < 8; ++t) a[t] = make_float4(0.f, 0.f, 0.f, 0.f);

    for (int c = 0; c < NCH; ++c) {
        // coalesced per-chunk range loads (chunk-major table)
        int sv = offcm[(size_t)c * Ntot + nodeBase + l32];
        int ev = offcm[(size_t)(c + 1) * Ntot + nodeBase + l32];
        #pragma unroll
        for (int t = 0; t < 8; ++t) {
            int js = __shfl(sv, 4 * t + g);
            int je = __shfl(ev, 4 * t + g);
            for (int j = js; j < je; ++j) {
                uint2 p = packed[j];
                float w = __uint_as_float(p.y);
                float4 v = *reinterpret_cast<const float4*>(hp + (size_t)p.x * 64);
                a[t].x = fmaf(w, v.x, a[t].x);
                a[t].y = fmaf(w, v.y, a[t].y);
                a[t].z = fmaf(w, v.z, a[t].z);
                a[t].w = fmaf(w, v.w, a[t].w);
            }
        }
        // soft grid barrier: align chunk windows across all blocks
        if (c + 1 < NCH) {
            __syncthreads();
            if (tid == 0) {
                atomicAdd(&bar[c], 1);
                int sp = 0;
                while (atomicAdd(&bar[c], 0) < nblk && ++sp < 256)
                    __builtin_amdgcn_s_sleep(8);
            }
            __syncthreads();
        }
    }

    const float4 bv = *reinterpret_cast<const float4*>(bias + fb);
    float4 pv = make_float4(0.f, 0.f, 0.f, 0.f);
    if (FUSE_SCORE) pv = *reinterpret_cast<const float4*>(pw + fb);
    #pragma unroll
    for (int t = 0; t < 8; ++t) {
        int node = nodeBase + 4 * t + g;
        if (node < N) {
            float d = dis[node];
            float4 h;
            h.x = fmaxf(fmaf(a[t].x, d, bv.x), 0.f);
            h.y = fmaxf(fmaf(a[t].y, d, bv.y), 0.f);
            h.z = fmaxf(fmaf(a[t].z, d, bv.z), 0.f);
            h.w = fmaxf(fmaf(a[t].w, d, bv.w), 0.f);
            if (FUSE_SCORE) {
                float s = h.x * pv.x + h.y * pv.y + h.z * pv.z + h.w * pv.w;
                #pragma unroll
                for (int m2 = 1; m2 <= 8; m2 <<= 1) s += __shfl_xor(s, m2);
                float sg = 1.0f / (1.0f + expf(-(s + pb[0])));
                h.x *= sg; h.y *= sg; h.z *= sg; h.w *= sg;
            }
            *reinterpret_cast<float4*>(Hout + (size_t)node * 64 + fb) = h;
        }
    }
}

// ---- per-graph max || mean pooling (batch sorted) --------------------------
__global__ void tpn_pool(const float* __restrict__ Hs, const int* __restrict__ batch,
                         int N, float* __restrict__ Gf) {
    int g = blockIdx.x;
    int s, e;
    {
        int lo = 0, hi = N;
        while (lo < hi) { int mid = (lo + hi) >> 1; if (batch[mid] < g) lo = mid + 1; else hi = mid; }
        s = lo;
        lo = 0; hi = N;
        while (lo < hi) { int mid = (lo + hi) >> 1; if (batch[mid] < g + 1) lo = mid + 1; else hi = mid; }
        e = lo;
    }
    int lane = threadIdx.x & 63;
    int w = threadIdx.x >> 6;  // 0..3
    float mx = -3.4e38f, sm = 0.0f;
    for (int i = s + w; i < e; i += 4) {
        float v = Hs[(size_t)i * 64 + lane];
        mx = fmaxf(mx, v);
        sm += v;
    }
    __shared__ float shm[4][64], shs[4][64];
    shm[w][lane] = mx; shs[w][lane] = sm;
    __syncthreads();
    if (w == 0) {
        mx = fmaxf(fmaxf(shm[0][lane], shm[1][lane]), fmaxf(shm[2][lane], shm[3][lane]));
        sm = shs[0][lane] + shs[1][lane] + shs[2][lane] + shs[3][lane];
        float c = (float)(e - s);
        float inv = 1.0f / fmaxf(c, 1.0f);
        Gf[g * 128 + lane]      = mx;
        Gf[g * 128 + 64 + lane] = sm * inv;
    }
}

// ---- final MLP: out = relu(G @ lw1 + lb1) @ lw2 + lb2 ----------------------
__global__ void tpn_mlp(const float* __restrict__ Gf, const float* __restrict__ lw1,
                        const float* __restrict__ lb1, const float* __restrict__ lw2,
                        const float* __restrict__ lb2, float* __restrict__ out,
                        int G, int C) {
    int wid = (blockIdx.x * blockDim.x + threadIdx.x) >> 6;
    int lane = threadIdx.x & 63;
    if (wid >= G) return;
    const float* gr = Gf + (size_t)wid * 128;
    float acc = lb1[lane];
    for (int k = 0; k < 128; k += 4) {
        float4 gv = *reinterpret_cast<const float4*>(gr + k);
        acc = fmaf(gv.x, lw1[(k + 0) * 64 + lane], acc);
        acc = fmaf(gv.y, lw1[(k + 1) * 64 + lane], acc);
        acc = fmaf(gv.z, lw1[(k + 2) * 64 + lane], acc);
        acc = fmaf(gv.w, lw1[(k + 3) * 64 + lane], acc);
    }
    float t = fmaxf(acc, 0.0f);
    for (int c = 0; c < C; ++c) {
        float v = t * lw2[lane * C + c];
        #pragma unroll
        for (int m = 32; m > 0; m >>= 1) v += __shfl_xor(v, m);
        if (lane == 0) out[wid * C + c] = v + lb2[c];
    }
}

// ---------------------------------------------------------------------------
extern "C" void kernel_launch(void* const* d_in, const int* in_sizes, int n_in,
                              void* d_out, int out_size, void* d_ws, size_t ws_size,
                              hipStream_t stream) {
    const float* x   = (const float*)d_in[0];
    const int*   ei  = (const int*)  d_in[1];
    const float* ew  = (const float*)d_in[2];
    const int*   bat = (const int*)  d_in[3];
    const float* W1  = (const float*)d_in[5];
    const float* b1  = (const float*)d_in[6];
    const float* W2  = (const float*)d_in[7];
    const float* b2  = (const float*)d_in[8];
    const float* pw  = (const float*)d_in[9];
    const float* pb  = (const float*)d_in[10];
    const float* lw1 = (const float*)d_in[11];
    const float* lb1 = (const float*)d_in[12];
    const float* lw2 = (const float*)d_in[13];
    const float* lb2 = (const float*)d_in[14];
    float* out = (float*)d_out;

    const int N    = in_sizes[3];
    const int E    = in_sizes[2];
    const int IN   = in_sizes[0] / N;   // 128
    const int C    = in_sizes[14];      // 2
    const int G    = out_size / C;      // 128
    const int NB   = (N + 255) >> 8;    // 391 bins of 256 nodes
    const int Ntot = NB << 8;           // 100096
    const int NCH  = (Ntot + (1 << CSH) - 1) >> CSH;  // 13 chunks (<=15 req.)

    // ---- workspace layout ----
    char* ws = (char*)d_ws;
    size_t o = 0;
    auto alloc = [&](size_t bytes) { void* p = ws + o; o = (o + bytes + 255) & ~(size_t)255; return p; };
    float* dis    = (float*)alloc((size_t)N * 4);
    int*   binCur = (int*)  alloc((size_t)NB_MAX * 4);
    int*   bar    = (int*)  alloc((size_t)64 * 4);       // adjacent to binCur
    int*   binOff = (int*)  alloc((size_t)NB_MAX * 4);
    float* Gf     = (float*)alloc((size_t)G * 128 * 4);
    int*   offcm  = (int*)  alloc((size_t)16 * Ntot * 4);  // chunk-major offsets
    uint2* packed = (uint2*)alloc((size_t)E * 8);
    float* hA     = (float*)alloc((size_t)N * 64 * 4);
    float* hB     = (float*)alloc((size_t)N * 64 * 4);
    // binned is dead after tpn_build -> alias it over hA/hB
    uint2* binned = (uint2*)hA;
    (void)n_in; (void)ws_size;

    // zero binCur + bar in one shot (they are adjacent allocations)
    (void)hipMemsetAsync(binCur, 0, (size_t)(NB_MAX + 64) * 4 + 256, stream);

    const int p1b   = (E + P1_CHUNK - 1) / P1_CHUNK;
    const int ggrid = (N + 63) / 64;      // gemm tiles
    const int ablk  = Ntot / 128;         // 782 agg blocks (128 nodes each)

    // CSR build: bin -> scan -> (node,chunk) sort + chunk-major offsets
    tpn_bin<<<p1b, TPN_BLK, 0, stream>>>(ei, ew, binCur, binned, E, NB);
    tpn_binscan<<<1, NB_MAX, 0, stream>>>(binCur, binOff, NB);
    tpn_build<<<NB, 256, 0, stream>>>(binned, binCur, binOff, packed, offcm, dis, N, Ntot);

    // layer 1: hA = dis * (x @ W1) ; hB = relu(dis*agg(hA) + b1)
    tpn_gemm_t<<<ggrid, 256, 0, stream>>>(x, W1, dis, hA, N, IN);
    tpn_aggc<false><<<ablk, 256, 0, stream>>>(packed, offcm, dis, hA, b1, pw, pb, hB,
                                              N, Ntot, NCH, bar, ablk);

    // layer 2: hA = dis * (hB @ W2) ; hB = score-gated relu(dis*agg(hA) + b2)
    tpn_gemm_t<<<ggrid, 256, 0, stream>>>(hB, W2, dis, hA, N, 64);
    tpn_aggc<true><<<ablk, 256, 0, stream>>>(packed, offcm, dis, hA, b2, pw, pb, hB,
                                             N, Ntot, NCH, bar + 16, ablk);

    // pooling + MLP head
    tpn_pool<<<G, TPN_BLK, 0, stream>>>(hB, bat, N, Gf);
    tpn_mlp<<<(G * 64 + TPN_BLK - 1) / TPN_BLK, TPN_BLK, 0, stream>>>(Gf, lw1, lb1, lw2, lb2, out, G, C);
}

// Round 13
// 1661.590 us; speedup vs baseline: 1.0176x; 1.0176x over previous
//
#include <hip/hip_runtime.h>
#include <math.h>

// ---------------------------------------------------------------------------
// TopoPoolNet: GCN(128->64) -> GCN(64->64) -> sigmoid score gate ->
//              per-graph max||mean pool -> MLP(128->64->2)
//
// Round-12: R11's chunk-phased agg cut FETCH 361->167MB (locality works) but
// serialized the gathers (748us, VALUBusy 2.8%). Now each chunk phase issues
// 4 predicated passes x 4 cells = 16 independent row-gathers per wave in
// flight (bounds known upfront -> no inter-pass dependence). Clamped index +
// zero weight for empty slots; rare >4-edge cells take a serial tail.
// Barrier/build/gemm/pool/mlp unchanged from R11.
// ---------------------------------------------------------------------------

#define TPN_BLK 256
#define P1_EPT  16                   // edges per thread in bin pass
#define P1_CHUNK (TPN_BLK * P1_EPT)  // 4096 edges per block
#define NB_MAX  512
#define BCAP    12288                // per-bin capacity (mean ~8184)
#define CSH     13                   // source chunk = 8192 nodes = 2 MB
#define NKEY    4096                 // 256 local nodes x 16 chunks

// ---- pass 1: block-level counting sort by bin (col>>8), coalesced out -----
__global__ __launch_bounds__(256)
void tpn_bin(const int* __restrict__ ei, const float* __restrict__ ew,
             int* __restrict__ binCur, uint2* __restrict__ binned,
             int E, int NB) {
    __shared__ uint2          sbuf[P1_CHUNK];      // 32 KB
    __shared__ unsigned short sbin[P1_CHUNK];      // 8 KB
    __shared__ int hist[NB_MAX];
    __shared__ int loff[NB_MAX];
    __shared__ int lrank[NB_MAX];
    __shared__ int gbase[NB_MAX];
    __shared__ int ssc[256];

    int tid = threadIdx.x;
    for (int b = tid; b < NB_MAX; b += 256) { hist[b] = 0; lrank[b] = 0; }
    __syncthreads();

    int base = blockIdx.x * P1_CHUNK;
    uint2 ed[P1_EPT];
    int   bn[P1_EPT];
    #pragma unroll
    for (int j = 0; j < P1_EPT; ++j) {
        int e = base + tid + j * 256;
        bn[j] = -1;
        if (e < E) {
            int r = ei[e], c = ei[E + e];
            bn[j] = c >> 8;
            ed[j] = make_uint2((unsigned)r | ((unsigned)(c & 255) << 17),
                               __float_as_uint(ew[e]));
            atomicAdd(&hist[bn[j]], 1);
        }
    }
    __syncthreads();
    {
        int b0 = 2 * tid, b1 = 2 * tid + 1;
        int h0 = hist[b0], h1 = hist[b1];
        int s = h0 + h1;
        ssc[tid] = s;
        __syncthreads();
        for (int st = 1; st < 256; st <<= 1) {
            int v = (tid >= st) ? ssc[tid - st] : 0;
            __syncthreads();
            ssc[tid] += v;
            __syncthreads();
        }
        int pre = ssc[tid] - s;
        loff[b0] = pre;
        loff[b1] = pre + h0;
    }
    __syncthreads();
    for (int b = tid; b < NB; b += 256) {
        int h = hist[b];
        if (h > 0) gbase[b] = atomicAdd(&binCur[b], h);
    }
    #pragma unroll
    for (int j = 0; j < P1_EPT; ++j) {
        if (bn[j] >= 0) {
            int p = loff[bn[j]] + atomicAdd(&lrank[bn[j]], 1);
            sbuf[p] = ed[j];
            sbin[p] = (unsigned short)bn[j];
        }
    }
    __syncthreads();
    int m = min(E - base, P1_CHUNK);
    for (int i = tid; i < m; i += 256) {
        uint2 u = sbuf[i];
        int b = sbin[i];
        int dst = gbase[b] + (i - loff[b]);
        if (dst < BCAP) binned[(size_t)b * BCAP + dst] = u;
    }
}

// ---- exclusive scan of bin counts (single block) ---------------------------
__global__ void tpn_binscan(const int* __restrict__ binCur, int* __restrict__ binOff,
                            int NB) {
    __shared__ int sh[NB_MAX];
    int t = threadIdx.x;
    int v = (t < NB) ? min(binCur[t], BCAP) : 0;
    sh[t] = v;
    __syncthreads();
    for (int st = 1; st < NB_MAX; st <<= 1) {
        int u = (t >= st) ? sh[t - st] : 0;
        __syncthreads();
        sh[t] += u;
        __syncthreads();
    }
    if (t < NB) binOff[t] = sh[t] - v;
}

// ---- pass 2: per-bin (node, source-chunk) counting sort + dis + offcm ------
__global__ __launch_bounds__(256)
void tpn_build(const uint2* __restrict__ binned, const int* __restrict__ binCur,
               const int* __restrict__ binOff, uint2* __restrict__ packed,
               int* __restrict__ offcm, float* __restrict__ dis,
               int N, int Ntot) {
    __shared__ int   kcnt[NKEY];    // 16 KB
    __shared__ int   koff[NKEY];    // 16 KB
    __shared__ int   krank[NKEY];   // 16 KB
    __shared__ float ldeg[256];
    __shared__ int   ssc[256];
    int b = blockIdx.x, tid = threadIdx.x;
    int m = min(binCur[b], BCAP);
    const uint2* src = binned + (size_t)b * BCAP;
    for (int i = tid; i < NKEY; i += 256) { kcnt[i] = 0; krank[i] = 0; }
    ldeg[tid] = 0.0f;
    __syncthreads();
    for (int i = tid; i < m; i += 256) {
        uint2 u = src[i];
        int ln = u.x >> 17;
        int ch = (u.x & 0x1FFFF) >> CSH;
        atomicAdd(&kcnt[(ln << 4) | ch], 1);
        atomicAdd(&ldeg[ln], __uint_as_float(u.y));
    }
    __syncthreads();
    {
        int base16 = tid << 4;
        int loc[16]; int s = 0;
        #pragma unroll
        for (int i = 0; i < 16; ++i) { loc[i] = s; s += kcnt[base16 + i]; }
        ssc[tid] = s;
        __syncthreads();
        for (int st = 1; st < 256; st <<= 1) {
            int v = (tid >= st) ? ssc[tid - st] : 0;
            __syncthreads();
            ssc[tid] += v;
            __syncthreads();
        }
        int pre = ssc[tid] - s;
        #pragma unroll
        for (int i = 0; i < 16; ++i) koff[base16 + i] = pre + loc[i];
    }
    __syncthreads();
    {
        int node = (b << 8) + tid;
        if (node < N) {
            float s = ldeg[tid];
            dis[node] = (s > 0.0f) ? rsqrtf(fmaxf(s, 1e-12f)) : 0.0f;
        }
    }
    int gb = binOff[b];
    for (int k = tid; k < NKEY; k += 256) {
        int ln = k >> 4, ch = k & 15;
        offcm[(size_t)ch * Ntot + (b << 8) + ln] = gb + koff[k];
    }
    for (int i = tid; i < m; i += 256) {
        uint2 u = src[i];
        int ln = u.x >> 17;
        int ch = (u.x & 0x1FFFF) >> CSH;
        int k = (ln << 4) | ch;
        int rk = atomicAdd(&krank[k], 1);
        packed[gb + koff[k] + rk] = make_uint2(u.x & 0x1FFFF, u.y);
    }
}

// ---- tiled GEMM: Y[n,f] = dis[n] * sum_k X[n,k]*W[k,f]; 64x64 tile ---------
__global__ __launch_bounds__(256, 4)
void tpn_gemm_t(const float* __restrict__ X, const float* __restrict__ W,
                const float* __restrict__ dis, float* __restrict__ Y,
                int N, int K) {
    __shared__ float sX[64][68];
    __shared__ float sW[64][64];
    const int t  = threadIdx.x;
    const int r  = t >> 4;
    const int cc = t & 15;
    const int fg = t & 15;
    const int ng = t >> 4;
    const int nb = blockIdx.x * 64;

    float acc[4][4] = {{0.f}};

    for (int kc = 0; kc < K; kc += 64) {
        __syncthreads();
        #pragma unroll
        for (int p = 0; p < 4; ++p) {
            int n = nb + r + p * 16;
            int ns = (n < N) ? n : (N - 1);
            float4 v = *reinterpret_cast<const float4*>(X + (size_t)ns * K + kc + 4 * cc);
            *reinterpret_cast<float4*>(&sX[r + p * 16][4 * cc]) = v;
        }
        #pragma unroll
        for (int p = 0; p < 4; ++p) {
            int k = kc + r + p * 16;
            float4 v = *reinterpret_cast<const float4*>(W + (size_t)k * 64 + 4 * cc);
            *reinterpret_cast<float4*>(&sW[r + p * 16][4 * cc]) = v;
        }
        __syncthreads();
        #pragma unroll 4
        for (int k = 0; k < 64; ++k) {
            float4 wv = *reinterpret_cast<const float4*>(&sW[k][4 * fg]);
            float x0 = sX[4 * ng + 0][k];
            float x1 = sX[4 * ng + 1][k];
            float x2 = sX[4 * ng + 2][k];
            float x3 = sX[4 * ng + 3][k];
            acc[0][0] = fmaf(x0, wv.x, acc[0][0]);
            acc[0][1] = fmaf(x0, wv.y, acc[0][1]);
            acc[0][2] = fmaf(x0, wv.z, acc[0][2]);
            acc[0][3] = fmaf(x0, wv.w, acc[0][3]);
            acc[1][0] = fmaf(x1, wv.x, acc[1][0]);
            acc[1][1] = fmaf(x1, wv.y, acc[1][1]);
            acc[1][2] = fmaf(x1, wv.z, acc[1][2]);
            acc[1][3] = fmaf(x1, wv.w, acc[1][3]);
            acc[2][0] = fmaf(x2, wv.x, acc[2][0]);
            acc[2][1] = fmaf(x2, wv.y, acc[2][1]);
            acc[2][2] = fmaf(x2, wv.z, acc[2][2]);
            acc[2][3] = fmaf(x2, wv.w, acc[2][3]);
            acc[3][0] = fmaf(x3, wv.x, acc[3][0]);
            acc[3][1] = fmaf(x3, wv.y, acc[3][1]);
            acc[3][2] = fmaf(x3, wv.z, acc[3][2]);
            acc[3][3] = fmaf(x3, wv.w, acc[3][3]);
        }
    }
    #pragma unroll
    for (int i = 0; i < 4; ++i) {
        int n = nb + 4 * ng + i;
        if (n < N) {
            float d = dis[n];
            float4 v = make_float4(acc[i][0] * d, acc[i][1] * d,
                                   acc[i][2] * d, acc[i][3] * d);
            *reinterpret_cast<float4*>(Y + (size_t)n * 64 + 4 * fg) = v;
        }
    }
}

// ---- chunk-phased aggregate with deep gather pipelining --------------------
// Wave owns 32 nodes (8 cells x 4 groups). Per chunk: 2 halves x 4 predicated
// passes -> 16 independent row-gathers in flight. Soft grid barrier between
// chunks (performance-only, bounded spin).
template <bool FUSE_SCORE>
__global__ __launch_bounds__(256, 4)
void tpn_aggc(const uint2* __restrict__ packed, const int* __restrict__ offcm,
              const float* __restrict__ dis, const float* __restrict__ Hin,
              const float* __restrict__ bias, const float* __restrict__ pw,
              const float* __restrict__ pb, float* __restrict__ Hout,
              int N, int Ntot, int NCH, int E,
              int* __restrict__ bar, int nblk) {
    const int tid  = threadIdx.x;
    const int wid  = blockIdx.x * 4 + (tid >> 6);
    const int lane = tid & 63;
    const int l32  = lane & 31;
    const int g    = lane >> 4;          // group 0..3 (node i%4 == g)
    const int fb   = (lane & 15) * 4;    // feature base
    const int nodeBase = wid * 32;
    const float* hp = Hin + fb;

    float4 a[8];
    #pragma unroll
    for (int t = 0; t < 8; ++t) a[t] = make_float4(0.f, 0.f, 0.f, 0.f);

    for (int c = 0; c < NCH; ++c) {
        int sv = offcm[(size_t)c * Ntot + nodeBase + l32];
        int ev = offcm[(size_t)(c + 1) * Ntot + nodeBase + l32];
        #pragma unroll
        for (int half = 0; half < 2; ++half) {
            int js[4], je[4];
            #pragma unroll
            for (int t = 0; t < 4; ++t) {
                js[t] = __shfl(sv, 4 * (4 * half + t) + g);
                je[t] = __shfl(ev, 4 * (4 * half + t) + g);
            }
            // 4 predicated passes: all loads independent -> 16 gathers in flight
            #pragma unroll
            for (int e = 0; e < 4; ++e) {
                uint2 pp[4];
                #pragma unroll
                for (int t = 0; t < 4; ++t) {
                    int idx = js[t] + e;
                    uint2 p = packed[min(idx, E - 1)];
                    if (idx >= je[t]) p.y = 0u;   // weight 0 -> no contribution
                    pp[t] = p;
                }
                #pragma unroll
                for (int t = 0; t < 4; ++t) {
                    float w = __uint_as_float(pp[t].y);
                    float4 v = *reinterpret_cast<const float4*>(hp + (size_t)pp[t].x * 64);
                    int at = 4 * half + t;
                    a[at].x = fmaf(w, v.x, a[at].x);
                    a[at].y = fmaf(w, v.y, a[at].y);
                    a[at].z = fmaf(w, v.z, a[at].z);
                    a[at].w = fmaf(w, v.w, a[at].w);
                }
            }
            // rare serial tail: cells with >4 edges in this chunk (~6% of edges)
            #pragma unroll
            for (int t = 0; t < 4; ++t) {
                int at = 4 * half + t;
                for (int j = js[t] + 4; j < je[t]; ++j) {
                    uint2 p = packed[j];
                    float w = __uint_as_float(p.y);
                    float4 v = *reinterpret_cast<const float4*>(hp + (size_t)p.x * 64);
                    a[at].x = fmaf(w, v.x, a[at].x);
                    a[at].y = fmaf(w, v.y, a[at].y);
                    a[at].z = fmaf(w, v.z, a[at].z);
                    a[at].w = fmaf(w, v.w, a[at].w);
                }
            }
        }
        // soft grid barrier (performance-only, bounded spin)
        if (c + 1 < NCH) {
            __syncthreads();
            if (tid == 0) {
                atomicAdd(&bar[c], 1);
                int sp = 0;
                while (atomicAdd(&bar[c], 0) < nblk && ++sp < 256)
                    __builtin_amdgcn_s_sleep(8);
            }
            __syncthreads();
        }
    }

    const float4 bv = *reinterpret_cast<const float4*>(bias + fb);
    float4 pv = make_float4(0.f, 0.f, 0.f, 0.f);
    if (FUSE_SCORE) pv = *reinterpret_cast<const float4*>(pw + fb);
    #pragma unroll
    for (int t = 0; t < 8; ++t) {
        int node = nodeBase + 4 * t + g;
        if (node < N) {
            float d = dis[node];
            float4 h;
            h.x = fmaxf(fmaf(a[t].x, d, bv.x), 0.f);
            h.y = fmaxf(fmaf(a[t].y, d, bv.y), 0.f);
            h.z = fmaxf(fmaf(a[t].z, d, bv.z), 0.f);
            h.w = fmaxf(fmaf(a[t].w, d, bv.w), 0.f);
            if (FUSE_SCORE) {
                float s = h.x * pv.x + h.y * pv.y + h.z * pv.z + h.w * pv.w;
                #pragma unroll
                for (int m2 = 1; m2 <= 8; m2 <<= 1) s += __shfl_xor(s, m2);
                float sg = 1.0f / (1.0f + expf(-(s + pb[0])));
                h.x *= sg; h.y *= sg; h.z *= sg; h.w *= sg;
            }
            *reinterpret_cast<float4*>(Hout + (size_t)node * 64 + fb) = h;
        }
    }
}

// ---- per-graph max || mean pooling (batch sorted) --------------------------
__global__ void tpn_pool(const float* __restrict__ Hs, const int* __restrict__ batch,
                         int N, float* __restrict__ Gf) {
    int g = blockIdx.x;
    int s, e;
    {
        int lo = 0, hi = N;
        while (lo < hi) { int mid = (lo + hi) >> 1; if (batch[mid] < g) lo = mid + 1; else hi = mid; }
        s = lo;
        lo = 0; hi = N;
        while (lo < hi) { int mid = (lo + hi) >> 1; if (batch[mid] < g + 1) lo = mid + 1; else hi = mid; }
        e = lo;
    }
    int lane = threadIdx.x & 63;
    int w = threadIdx.x >> 6;  // 0..3
    float mx = -3.4e38f, sm = 0.0f;
    for (int i = s + w; i < e; i += 4) {
        float v = Hs[(size_t)i * 64 + lane];
        mx = fmaxf(mx, v);
        sm += v;
    }
    __shared__ float shm[4][64], shs[4][64];
    shm[w][lane] = mx; shs[w][lane] = sm;
    __syncthreads();
    if (w == 0) {
        mx = fmaxf(fmaxf(shm[0][lane], shm[1][lane]), fmaxf(shm[2][lane], shm[3][lane]));
        sm = shs[0][lane] + shs[1][lane] + shs[2][lane] + shs[3][lane];
        float c = (float)(e - s);
        float inv = 1.0f / fmaxf(c, 1.0f);
        Gf[g * 128 + lane]      = mx;
        Gf[g * 128 + 64 + lane] = sm * inv;
    }
}

// ---- final MLP: out = relu(G @ lw1 + lb1) @ lw2 + lb2 ----------------------
__global__ void tpn_mlp(const float* __restrict__ Gf, const float* __restrict__ lw1,
                        const float* __restrict__ lb1, const float* __restrict__ lw2,
                        const float* __restrict__ lb2, float* __restrict__ out,
                        int G, int C) {
    int wid = (blockIdx.x * blockDim.x + threadIdx.x) >> 6;
    int lane = threadIdx.x & 63;
    if (wid >= G) return;
    const float* gr = Gf + (size_t)wid * 128;
    float acc = lb1[lane];
    for (int k = 0; k < 128; k += 4) {
        float4 gv = *reinterpret_cast<const float4*>(gr + k);
        acc = fmaf(gv.x, lw1[(k + 0) * 64 + lane], acc);
        acc = fmaf(gv.y, lw1[(k + 1) * 64 + lane], acc);
        acc = fmaf(gv.z, lw1[(k + 2) * 64 + lane], acc);
        acc = fmaf(gv.w, lw1[(k + 3) * 64 + lane], acc);
    }
    float t = fmaxf(acc, 0.0f);
    for (int c = 0; c < C; ++c) {
        float v = t * lw2[lane * C + c];
        #pragma unroll
        for (int m = 32; m > 0; m >>= 1) v += __shfl_xor(v, m);
        if (lane == 0) out[wid * C + c] = v + lb2[c];
    }
}

// ---------------------------------------------------------------------------
extern "C" void kernel_launch(void* const* d_in, const int* in_sizes, int n_in,
                              void* d_out, int out_size, void* d_ws, size_t ws_size,
                              hipStream_t stream) {
    const float* x   = (const float*)d_in[0];
    const int*   ei  = (const int*)  d_in[1];
    const float* ew  = (const float*)d_in[2];
    const int*   bat = (const int*)  d_in[3];
    const float* W1  = (const float*)d_in[5];
    const float* b1  = (const float*)d_in[6];
    const float* W2  = (const float*)d_in[7];
    const float* b2  = (const float*)d_in[8];
    const float* pw  = (const float*)d_in[9];
    const float* pb  = (const float*)d_in[10];
    const float* lw1 = (const float*)d_in[11];
    const float* lb1 = (const float*)d_in[12];
    const float* lw2 = (const float*)d_in[13];
    const float* lb2 = (const float*)d_in[14];
    float* out = (float*)d_out;

    const int N    = in_sizes[3];
    const int E    = in_sizes[2];
    const int IN   = in_sizes[0] / N;   // 128
    const int C    = in_sizes[14];      // 2
    const int G    = out_size / C;      // 128
    const int NB   = (N + 255) >> 8;    // 391 bins of 256 nodes
    const int Ntot = NB << 8;           // 100096
    const int NCH  = (Ntot + (1 << CSH) - 1) >> CSH;  // 13 chunks

    // ---- workspace layout ----
    char* ws = (char*)d_ws;
    size_t o = 0;
    auto alloc = [&](size_t bytes) { void* p = ws + o; o = (o + bytes + 255) & ~(size_t)255; return p; };
    float* dis    = (float*)alloc((size_t)N * 4);
    int*   binCur = (int*)  alloc((size_t)NB_MAX * 4);
    int*   bar    = (int*)  alloc((size_t)64 * 4);       // adjacent to binCur
    int*   binOff = (int*)  alloc((size_t)NB_MAX * 4);
    float* Gf     = (float*)alloc((size_t)G * 128 * 4);
    int*   offcm  = (int*)  alloc((size_t)16 * Ntot * 4);  // chunk-major offsets
    uint2* packed = (uint2*)alloc((size_t)E * 8);
    float* hA     = (float*)alloc((size_t)N * 64 * 4);
    float* hB     = (float*)alloc((size_t)N * 64 * 4);
    uint2* binned = (uint2*)hA;   // dead after tpn_build
    (void)n_in; (void)ws_size;

    (void)hipMemsetAsync(binCur, 0, (size_t)(NB_MAX + 64) * 4 + 256, stream);

    const int p1b   = (E + P1_CHUNK - 1) / P1_CHUNK;
    const int ggrid = (N + 63) / 64;      // gemm tiles
    const int ablk  = Ntot / 128;         // 782 agg blocks (128 nodes each)

    // CSR build: bin -> scan -> (node,chunk) sort + chunk-major offsets
    tpn_bin<<<p1b, TPN_BLK, 0, stream>>>(ei, ew, binCur, binned, E, NB);
    tpn_binscan<<<1, NB_MAX, 0, stream>>>(binCur, binOff, NB);
    tpn_build<<<NB, 256, 0, stream>>>(binned, binCur, binOff, packed, offcm, dis, N, Ntot);

    // layer 1: hA = dis * (x @ W1) ; hB = relu(dis*agg(hA) + b1)
    tpn_gemm_t<<<ggrid, 256, 0, stream>>>(x, W1, dis, hA, N, IN);
    tpn_aggc<false><<<ablk, 256, 0, stream>>>(packed, offcm, dis, hA, b1, pw, pb, hB,
                                              N, Ntot, NCH, E, bar, ablk);

    // layer 2: hA = dis * (hB @ W2) ; hB = score-gated relu(dis*agg(hA) + b2)
    tpn_gemm_t<<<ggrid, 256, 0, stream>>>(hB, W2, dis, hA, N, 64);
    tpn_aggc<true><<<ablk, 256, 0, stream>>>(packed, offcm, dis, hA, b2, pw, pb, hB,
                                             N, Ntot, NCH, E, bar + 16, ablk);

    // pooling + MLP head
    tpn_pool<<<G, TPN_BLK, 0, stream>>>(hB, bat, N, Gf);
    tpn_mlp<<<(G * 64 + TPN_BLK - 1) / TPN_BLK, TPN_BLK, 0, stream>>>(Gf, lw1, lb1, lw2, lb2, out, G, C);
}

// Round 14
// 419.398 us; speedup vs baseline: 4.0318x; 3.9618x over previous
//
#include <hip/hip_runtime.h>
#include <math.h>

// ---------------------------------------------------------------------------
// TopoPoolNet: GCN(128->64) -> GCN(64->64) -> sigmoid score gate ->
//              per-graph max||mean pool -> MLP(128->64->2)
//
// Round-13: consolidation on the best-known structure (R8, 419us).
// R9-R12 locality experiments all regressed (LDS atomics serialize; phased
// barriers kill MLP; fixed-pass padding wastes gathers). Changes vs R8:
//  * agg: unroll 16 edges -> 4 independent pack+gather chains in flight.
//  * bin: 8192 edges/block (halves reservation atomics + scan overhead).
// ---------------------------------------------------------------------------

#define TPN_BLK 256
#define P1_EPT  32                   // edges per thread in bin pass
#define P1_CHUNK (TPN_BLK * P1_EPT)  // 8192 edges per block
#define NB_MAX  512
#define BCAP    12288                // per-bin capacity (mean ~8184)

// ---- pass 1: block-level counting sort by bin (col>>8), coalesced out -----
__global__ __launch_bounds__(256)
void tpn_bin(const int* __restrict__ ei, const float* __restrict__ ew,
             int* __restrict__ binCur, uint2* __restrict__ binned,
             int E, int NB) {
    __shared__ uint2          sbuf[P1_CHUNK];      // 64 KB
    __shared__ unsigned char  sbin2[P1_CHUNK];     // 8 KB (bin - base, <512)
    __shared__ unsigned char  sbinhi[P1_CHUNK / 8];// bit: bin >= 256? packed
    __shared__ int hist[NB_MAX];
    __shared__ int loff[NB_MAX];
    __shared__ int lrank[NB_MAX];
    __shared__ int gbase[NB_MAX];
    __shared__ int ssc[256];

    int tid = threadIdx.x;
    for (int b = tid; b < NB_MAX; b += 256) { hist[b] = 0; lrank[b] = 0; }
    __syncthreads();

    int base = blockIdx.x * P1_CHUNK;
    uint2 ed[P1_EPT];
    short bn[P1_EPT];
    #pragma unroll
    for (int j = 0; j < P1_EPT; ++j) {
        int e = base + tid + j * 256;
        bn[j] = -1;
        if (e < E) {
            int r = ei[e], c = ei[E + e];
            bn[j] = (short)(c >> 8);
            ed[j] = make_uint2((unsigned)r | ((unsigned)(c & 255) << 17),
                               __float_as_uint(ew[e]));
            atomicAdd(&hist[bn[j]], 1);
        }
    }
    __syncthreads();
    // exclusive scan of hist[0..NB_MAX) -> loff (thread t owns bins 2t, 2t+1)
    {
        int b0 = 2 * tid, b1 = 2 * tid + 1;
        int h0 = hist[b0], h1 = hist[b1];
        int s = h0 + h1;
        ssc[tid] = s;
        __syncthreads();
        for (int st = 1; st < 256; st <<= 1) {
            int v = (tid >= st) ? ssc[tid - st] : 0;
            __syncthreads();
            ssc[tid] += v;
            __syncthreads();
        }
        int pre = ssc[tid] - s;
        loff[b0] = pre;
        loff[b1] = pre + h0;
    }
    __syncthreads();
    // reserve global space per (block, bin): one far atomic each
    for (int b = tid; b < NB; b += 256) {
        int h = hist[b];
        if (h > 0) gbase[b] = atomicAdd(&binCur[b], h);
    }
    if (tid < P1_CHUNK / 8 / 256 * 256 || true) {
        for (int i = tid; i < P1_CHUNK / 8; i += 256) sbinhi[i] = 0;
    }
    __syncthreads();
    // scatter into LDS, sorted by bin (store 9-bit bin as 8+1 packed bits)
    #pragma unroll
    for (int j = 0; j < P1_EPT; ++j) {
        if (bn[j] >= 0) {
            int p = loff[bn[j]] + atomicAdd(&lrank[bn[j]], 1);
            sbuf[p] = ed[j];
            sbin2[p] = (unsigned char)(bn[j] & 255);
            if (bn[j] >= 256) atomicOr((int*)&sbinhi[(p >> 3) & ~3],
                                       1 << ((p & 31)));
        }
    }
    __syncthreads();
    // coalesced writeout: position i belongs to bin sbin[i]
    int m = min(E - base, P1_CHUNK);
    for (int i = tid; i < m; i += 256) {
        uint2 u = sbuf[i];
        int hi = (((const int*)sbinhi)[i >> 5] >> (i & 31)) & 1;
        int b = sbin2[i] + (hi << 8);
        int dst = gbase[b] + (i - loff[b]);
        if (dst < BCAP) binned[(size_t)b * BCAP + dst] = u;
    }
}

// ---- exclusive scan of bin counts (single block) ---------------------------
__global__ void tpn_binscan(const int* __restrict__ binCur, int* __restrict__ binOff,
                            int NB) {
    __shared__ int sh[NB_MAX];
    int t = threadIdx.x;
    int v = (t < NB) ? min(binCur[t], BCAP) : 0;
    sh[t] = v;
    __syncthreads();
    for (int st = 1; st < NB_MAX; st <<= 1) {
        int u = (t >= st) ? sh[t - st] : 0;
        __syncthreads();
        sh[t] += u;
        __syncthreads();
    }
    if (t < NB) binOff[t] = sh[t] - v;
}

// ---- pass 2: per-bin packed CSR build + dis --------------------------------
__global__ void tpn_build(const uint2* __restrict__ binned, const int* __restrict__ binCur,
                          const int* __restrict__ binOff, uint2* __restrict__ packed,
                          int* __restrict__ off, int* __restrict__ cnt,
                          float* __restrict__ dis, int N) {
    __shared__ int   lcnt[256];
    __shared__ int   loff[256];
    __shared__ int   lrank[256];
    __shared__ int   lincl[256];
    __shared__ float ldeg[256];
    int b = blockIdx.x, tid = threadIdx.x;
    int m = min(binCur[b], BCAP);
    const uint2* src = binned + (size_t)b * BCAP;
    lcnt[tid] = 0; lrank[tid] = 0; ldeg[tid] = 0.0f;
    __syncthreads();
    for (int i = tid; i < m; i += 256) {
        uint2 u = src[i];
        int ln = u.x >> 17;
        atomicAdd(&lcnt[ln], 1);
        atomicAdd(&ldeg[ln], __uint_as_float(u.y));
    }
    __syncthreads();
    lincl[tid] = lcnt[tid];
    __syncthreads();
    for (int st = 1; st < 256; st <<= 1) {
        int u = (tid >= st) ? lincl[tid - st] : 0;
        __syncthreads();
        lincl[tid] += u;
        __syncthreads();
    }
    int excl = lincl[tid] - lcnt[tid];
    loff[tid] = excl;
    int node = (b << 8) + tid;
    if (node < N) {
        off[node] = binOff[b] + excl;
        cnt[node] = lcnt[tid];
        float s = ldeg[tid];
        dis[node] = (s > 0.0f) ? rsqrtf(fmaxf(s, 1e-12f)) : 0.0f;
    }
    __syncthreads();
    int gbase = binOff[b];
    for (int i = tid; i < m; i += 256) {
        uint2 u = src[i];
        int ln = u.x >> 17;
        int rk = atomicAdd(&lrank[ln], 1);
        packed[gbase + loff[ln] + rk] = make_uint2(u.x & 0x1FFFF, u.y);
    }
}

// ---- tiled GEMM: Y[n,f] = dis[n] * sum_k X[n,k]*W[k,f]; 64x64 tile ---------
__global__ __launch_bounds__(256, 4)
void tpn_gemm_t(const float* __restrict__ X, const float* __restrict__ W,
                const float* __restrict__ dis, float* __restrict__ Y,
                int N, int K) {
    __shared__ float sX[64][68];
    __shared__ float sW[64][64];
    const int t  = threadIdx.x;
    const int r  = t >> 4;
    const int cc = t & 15;
    const int fg = t & 15;
    const int ng = t >> 4;
    const int nb = blockIdx.x * 64;

    float acc[4][4] = {{0.f}};

    for (int kc = 0; kc < K; kc += 64) {
        __syncthreads();
        #pragma unroll
        for (int p = 0; p < 4; ++p) {
            int n = nb + r + p * 16;
            int ns = (n < N) ? n : (N - 1);
            float4 v = *reinterpret_cast<const float4*>(X + (size_t)ns * K + kc + 4 * cc);
            *reinterpret_cast<float4*>(&sX[r + p * 16][4 * cc]) = v;
        }
        #pragma unroll
        for (int p = 0; p < 4; ++p) {
            int k = kc + r + p * 16;
            float4 v = *reinterpret_cast<const float4*>(W + (size_t)k * 64 + 4 * cc);
            *reinterpret_cast<float4*>(&sW[r + p * 16][4 * cc]) = v;
        }
        __syncthreads();
        #pragma unroll 4
        for (int k = 0; k < 64; ++k) {
            float4 wv = *reinterpret_cast<const float4*>(&sW[k][4 * fg]);
            float x0 = sX[4 * ng + 0][k];
            float x1 = sX[4 * ng + 1][k];
            float x2 = sX[4 * ng + 2][k];
            float x3 = sX[4 * ng + 3][k];
            acc[0][0] = fmaf(x0, wv.x, acc[0][0]);
            acc[0][1] = fmaf(x0, wv.y, acc[0][1]);
            acc[0][2] = fmaf(x0, wv.z, acc[0][2]);
            acc[0][3] = fmaf(x0, wv.w, acc[0][3]);
            acc[1][0] = fmaf(x1, wv.x, acc[1][0]);
            acc[1][1] = fmaf(x1, wv.y, acc[1][1]);
            acc[1][2] = fmaf(x1, wv.z, acc[1][2]);
            acc[1][3] = fmaf(x1, wv.w, acc[1][3]);
            acc[2][0] = fmaf(x2, wv.x, acc[2][0]);
            acc[2][1] = fmaf(x2, wv.y, acc[2][1]);
            acc[2][2] = fmaf(x2, wv.z, acc[2][2]);
            acc[2][3] = fmaf(x2, wv.w, acc[2][3]);
            acc[3][0] = fmaf(x3, wv.x, acc[3][0]);
            acc[3][1] = fmaf(x3, wv.y, acc[3][1]);
            acc[3][2] = fmaf(x3, wv.z, acc[3][2]);
            acc[3][3] = fmaf(x3, wv.w, acc[3][3]);
        }
    }
    #pragma unroll
    for (int i = 0; i < 4; ++i) {
        int n = nb + 4 * ng + i;
        if (n < N) {
            float d = dis[n];
            float4 v = make_float4(acc[i][0] * d, acc[i][1] * d,
                                   acc[i][2] * d, acc[i][3] * d);
            *reinterpret_cast<float4*>(Y + (size_t)n * 64 + 4 * fg) = v;
        }
    }
}

// ---- aggregate: wave/node, 16 lanes x float4, 4 indep gather chains --------
template <bool FUSE_SCORE>
__global__ __launch_bounds__(256)
void tpn_agg(const uint2* __restrict__ packed, const int* __restrict__ off,
             const int* __restrict__ cnt, const float* __restrict__ dis,
             const float* __restrict__ Hin, const float* __restrict__ bias,
             const float* __restrict__ pw, const float* __restrict__ pb,
             float* __restrict__ Hout, int N) {
    int wid = (blockIdx.x * blockDim.x + threadIdx.x) >> 6;
    int lane = threadIdx.x & 63;
    if (wid >= N) return;
    const int eg = lane >> 4;        // edge slot 0..3
    const int fb = (lane & 15) * 4;  // feature base: fb..fb+3
    int start = off[wid], n = cnt[wid];
    const uint2* b = packed + start;
    const float* hp = Hin + fb;
    float dc = dis[wid];             // hoisted, independent load

    float4 A0 = {0.f, 0.f, 0.f, 0.f};
    float4 A1 = {0.f, 0.f, 0.f, 0.f};
    float4 A2 = {0.f, 0.f, 0.f, 0.f};
    float4 A3 = {0.f, 0.f, 0.f, 0.f};
    int j = 0;
    for (; j + 16 <= n; j += 16) {
        // 4 independent pack loads, then 4 independent row gathers
        uint2 p0 = b[j + eg];
        uint2 p1 = b[j + 4 + eg];
        uint2 p2 = b[j + 8 + eg];
        uint2 p3 = b[j + 12 + eg];
        float4 v0 = *reinterpret_cast<const float4*>(hp + (size_t)p0.x * 64);
        float4 v1 = *reinterpret_cast<const float4*>(hp + (size_t)p1.x * 64);
        float4 v2 = *reinterpret_cast<const float4*>(hp + (size_t)p2.x * 64);
        float4 v3 = *reinterpret_cast<const float4*>(hp + (size_t)p3.x * 64);
        float w0 = __uint_as_float(p0.y);
        float w1 = __uint_as_float(p1.y);
        float w2 = __uint_as_float(p2.y);
        float w3 = __uint_as_float(p3.y);
        A0.x = fmaf(w0, v0.x, A0.x); A0.y = fmaf(w0, v0.y, A0.y);
        A0.z = fmaf(w0, v0.z, A0.z); A0.w = fmaf(w0, v0.w, A0.w);
        A1.x = fmaf(w1, v1.x, A1.x); A1.y = fmaf(w1, v1.y, A1.y);
        A1.z = fmaf(w1, v1.z, A1.z); A1.w = fmaf(w1, v1.w, A1.w);
        A2.x = fmaf(w2, v2.x, A2.x); A2.y = fmaf(w2, v2.y, A2.y);
        A2.z = fmaf(w2, v2.z, A2.z); A2.w = fmaf(w2, v2.w, A2.w);
        A3.x = fmaf(w3, v3.x, A3.x); A3.y = fmaf(w3, v3.y, A3.y);
        A3.z = fmaf(w3, v3.z, A3.z); A3.w = fmaf(w3, v3.w, A3.w);
    }
    for (; j + 8 <= n; j += 8) {
        uint2 p0 = b[j + eg];
        uint2 p1 = b[j + 4 + eg];
        float4 v0 = *reinterpret_cast<const float4*>(hp + (size_t)p0.x * 64);
        float4 v1 = *reinterpret_cast<const float4*>(hp + (size_t)p1.x * 64);
        float w0 = __uint_as_float(p0.y);
        float w1 = __uint_as_float(p1.y);
        A0.x = fmaf(w0, v0.x, A0.x); A0.y = fmaf(w0, v0.y, A0.y);
        A0.z = fmaf(w0, v0.z, A0.z); A0.w = fmaf(w0, v0.w, A0.w);
        A1.x = fmaf(w1, v1.x, A1.x); A1.y = fmaf(w1, v1.y, A1.y);
        A1.z = fmaf(w1, v1.z, A1.z); A1.w = fmaf(w1, v1.w, A1.w);
    }
    for (; j < n; j += 4) {
        int idx = j + eg;
        uint2 p = (idx < n) ? b[idx] : make_uint2(0u, 0u);  // w=0 for pad lanes
        float4 v = *reinterpret_cast<const float4*>(hp + (size_t)p.x * 64);
        float w = __uint_as_float(p.y);
        A0.x = fmaf(w, v.x, A0.x); A0.y = fmaf(w, v.y, A0.y);
        A0.z = fmaf(w, v.z, A0.z); A0.w = fmaf(w, v.w, A0.w);
    }
    float4 acc;
    acc.x = (A0.x + A1.x) + (A2.x + A3.x);
    acc.y = (A0.y + A1.y) + (A2.y + A3.y);
    acc.z = (A0.z + A1.z) + (A2.z + A3.z);
    acc.w = (A0.w + A1.w) + (A2.w + A3.w);
    // fold the 4 edge slots (lanes ^16, ^32)
    acc.x += __shfl_xor(acc.x, 16); acc.x += __shfl_xor(acc.x, 32);
    acc.y += __shfl_xor(acc.y, 16); acc.y += __shfl_xor(acc.y, 32);
    acc.z += __shfl_xor(acc.z, 16); acc.z += __shfl_xor(acc.z, 32);
    acc.w += __shfl_xor(acc.w, 16); acc.w += __shfl_xor(acc.w, 32);

    const float4 bv = *reinterpret_cast<const float4*>(bias + fb);
    float4 h;
    h.x = fmaxf(fmaf(acc.x, dc, bv.x), 0.0f);
    h.y = fmaxf(fmaf(acc.y, dc, bv.y), 0.0f);
    h.z = fmaxf(fmaf(acc.z, dc, bv.z), 0.0f);
    h.w = fmaxf(fmaf(acc.w, dc, bv.w), 0.0f);
    if (FUSE_SCORE) {
        const float4 pv = *reinterpret_cast<const float4*>(pw + fb);
        float t = h.x * pv.x + h.y * pv.y + h.z * pv.z + h.w * pv.w;
        #pragma unroll
        for (int m = 1; m <= 8; m <<= 1) t += __shfl_xor(t, m);  // 16-lane group
        float s = 1.0f / (1.0f + expf(-(t + pb[0])));
        h.x *= s; h.y *= s; h.z *= s; h.w *= s;
    }
    if (eg == 0)
        *reinterpret_cast<float4*>(Hout + (size_t)wid * 64 + fb) = h;
}

// ---- per-graph max || mean pooling (batch sorted) --------------------------
__global__ void tpn_pool(const float* __restrict__ Hs, const int* __restrict__ batch,
                         int N, float* __restrict__ Gf) {
    int g = blockIdx.x;
    int s, e;
    {
        int lo = 0, hi = N;
        while (lo < hi) { int mid = (lo + hi) >> 1; if (batch[mid] < g) lo = mid + 1; else hi = mid; }
        s = lo;
        lo = 0; hi = N;
        while (lo < hi) { int mid = (lo + hi) >> 1; if (batch[mid] < g + 1) lo = mid + 1; else hi = mid; }
        e = lo;
    }
    int lane = threadIdx.x & 63;
    int w = threadIdx.x >> 6;  // 0..3
    float mx = -3.4e38f, sm = 0.0f;
    for (int i = s + w; i < e; i += 4) {
        float v = Hs[(size_t)i * 64 + lane];
        mx = fmaxf(mx, v);
        sm += v;
    }
    __shared__ float shm[4][64], shs[4][64];
    shm[w][lane] = mx; shs[w][lane] = sm;
    __syncthreads();
    if (w == 0) {
        mx = fmaxf(fmaxf(shm[0][lane], shm[1][lane]), fmaxf(shm[2][lane], shm[3][lane]));
        sm = shs[0][lane] + shs[1][lane] + shs[2][lane] + shs[3][lane];
        float c = (float)(e - s);
        float inv = 1.0f / fmaxf(c, 1.0f);
        Gf[g * 128 + lane]      = mx;
        Gf[g * 128 + 64 + lane] = sm * inv;
    }
}

// ---- final MLP: out = relu(G @ lw1 + lb1) @ lw2 + lb2 ----------------------
__global__ void tpn_mlp(const float* __restrict__ Gf, const float* __restrict__ lw1,
                        const float* __restrict__ lb1, const float* __restrict__ lw2,
                        const float* __restrict__ lb2, float* __restrict__ out,
                        int G, int C) {
    int wid = (blockIdx.x * blockDim.x + threadIdx.x) >> 6;
    int lane = threadIdx.x & 63;
    if (wid >= G) return;
    const float* gr = Gf + (size_t)wid * 128;
    float acc = lb1[lane];
    for (int k = 0; k < 128; k += 4) {
        float4 gv = *reinterpret_cast<const float4*>(gr + k);
        acc = fmaf(gv.x, lw1[(k + 0) * 64 + lane], acc);
        acc = fmaf(gv.y, lw1[(k + 1) * 64 + lane], acc);
        acc = fmaf(gv.z, lw1[(k + 2) * 64 + lane], acc);
        acc = fmaf(gv.w, lw1[(k + 3) * 64 + lane], acc);
    }
    float t = fmaxf(acc, 0.0f);
    for (int c = 0; c < C; ++c) {
        float v = t * lw2[lane * C + c];
        #pragma unroll
        for (int m = 32; m > 0; m >>= 1) v += __shfl_xor(v, m);
        if (lane == 0) out[wid * C + c] = v + lb2[c];
    }
}

// ---------------------------------------------------------------------------
extern "C" void kernel_launch(void* const* d_in, const int* in_sizes, int n_in,
                              void* d_out, int out_size, void* d_ws, size_t ws_size,
                              hipStream_t stream) {
    const float* x   = (const float*)d_in[0];
    const int*   ei  = (const int*)  d_in[1];
    const float* ew  = (const float*)d_in[2];
    const int*   bat = (const int*)  d_in[3];
    const float* W1  = (const float*)d_in[5];
    const float* b1  = (const float*)d_in[6];
    const float* W2  = (const float*)d_in[7];
    const float* b2  = (const float*)d_in[8];
    const float* pw  = (const float*)d_in[9];
    const float* pb  = (const float*)d_in[10];
    const float* lw1 = (const float*)d_in[11];
    const float* lb1 = (const float*)d_in[12];
    const float* lw2 = (const float*)d_in[13];
    const float* lb2 = (const float*)d_in[14];
    float* out = (float*)d_out;

    const int N  = in_sizes[3];
    const int E  = in_sizes[2];
    const int IN = in_sizes[0] / N;   // 128
    const int C  = in_sizes[14];      // 2
    const int G  = out_size / C;      // 128
    const int NB = (N + 255) >> 8;    // bins of 256 nodes

    // ---- workspace layout ----
    char* ws = (char*)d_ws;
    size_t o = 0;
    auto alloc = [&](size_t bytes) { void* p = ws + o; o = (o + bytes + 255) & ~(size_t)255; return p; };
    int*   off    = (int*)  alloc((size_t)N * 4);
    int*   cnt    = (int*)  alloc((size_t)N * 4);
    float* dis    = (float*)alloc((size_t)N * 4);
    int*   binCur = (int*)  alloc((size_t)NB_MAX * 4);
    int*   binOff = (int*)  alloc((size_t)NB_MAX * 4);
    float* Gf     = (float*)alloc((size_t)G * 128 * 4);
    uint2* packed = (uint2*)alloc((size_t)E * 8);
    float* hA     = (float*)alloc((size_t)N * 64 * 4);
    float* hB     = (float*)alloc((size_t)N * 64 * 4);
    // binned is dead after tpn_build -> alias it over hA/hB
    uint2* binned = (uint2*)hA;
    (void)n_in; (void)ws_size;

    (void)hipMemsetAsync(binCur, 0, (size_t)NB_MAX * 4, stream);

    const int p1b   = (E + P1_CHUNK - 1) / P1_CHUNK;
    const int ggrid = (N + 63) / 64;                        // gemm tiles
    const int agrid = (N * 64 + TPN_BLK - 1) / TPN_BLK;     // wave per node

    // CSR build: bin (LDS sort, coalesced) -> scan -> build
    tpn_bin<<<p1b, TPN_BLK, 0, stream>>>(ei, ew, binCur, binned, E, NB);
    tpn_binscan<<<1, NB_MAX, 0, stream>>>(binCur, binOff, NB);
    tpn_build<<<NB, 256, 0, stream>>>(binned, binCur, binOff, packed, off, cnt, dis, N);

    // layer 1: hA = dis * (x @ W1) ; hB = relu(dis*agg(hA) + b1)
    tpn_gemm_t<<<ggrid, 256, 0, stream>>>(x, W1, dis, hA, N, IN);
    tpn_agg<false><<<agrid, TPN_BLK, 0, stream>>>(packed, off, cnt, dis, hA, b1, pw, pb, hB, N);

    // layer 2: hA = dis * (hB @ W2) ; hB = score-gated relu(dis*agg(hA) + b2)
    tpn_gemm_t<<<ggrid, 256, 0, stream>>>(hB, W2, dis, hA, N, 64);
    tpn_agg<true><<<agrid, TPN_BLK, 0, stream>>>(packed, off, cnt, dis, hA, b2, pw, pb, hB, N);

    // pooling + MLP head
    tpn_pool<<<G, TPN_BLK, 0, stream>>>(hB, bat, N, Gf);
    tpn_mlp<<<(G * 64 + TPN_BLK - 1) / TPN_BLK, TPN_BLK, 0, stream>>>(Gf, lw1, lb1, lw2, lb2, out, G, C);
}

// Round 15
// 409.301 us; speedup vs baseline: 4.1312x; 1.0247x over previous
//
#include <hip/hip_runtime.h>
#include <math.h>

// ---------------------------------------------------------------------------
// TopoPoolNet: GCN(128->64) -> GCN(64->64) -> sigmoid score gate ->
//              per-graph max||mean pool -> MLP(128->64->2)
//
// Round-14: agg is at its structural floor (FETCH invariant 361MB across 6
// variants; L2-miss path ~3.6 TB/s). Attack the ~205us non-agg pot:
//  * bin reverted to proven R8 4096-edge LDS counting sort (R13's 8192
//    variant cost ~6us via occupancy drop).
//  * gemm2 FUSED into agg1 epilogue: after the shfl_xor folds every lane
//    holds the full hB row -> compute dis*(hB@W2) inline (16 quad-broadcasts
//    x 4 L1-resident W2 loads x 4 FMA) in the gather-latency shadow. Deletes
//    the gemm2 dispatch + its 25.6MB read + a serialization point.
// ---------------------------------------------------------------------------

#define TPN_BLK 256
#define P1_EPT  16                   // edges per thread in bin pass
#define P1_CHUNK (TPN_BLK * P1_EPT)  // 4096 edges per block
#define NB_MAX  512
#define BCAP    12288                // per-bin capacity (mean ~8184)

// ---- pass 1: block-level counting sort by bin (col>>8), coalesced out -----
__global__ __launch_bounds__(256)
void tpn_bin(const int* __restrict__ ei, const float* __restrict__ ew,
             int* __restrict__ binCur, uint2* __restrict__ binned,
             int E, int NB) {
    __shared__ uint2          sbuf[P1_CHUNK];      // 32 KB
    __shared__ unsigned short sbin[P1_CHUNK];      // 8 KB
    __shared__ int hist[NB_MAX];
    __shared__ int loff[NB_MAX];
    __shared__ int lrank[NB_MAX];
    __shared__ int gbase[NB_MAX];
    __shared__ int ssc[256];

    int tid = threadIdx.x;
    for (int b = tid; b < NB_MAX; b += 256) { hist[b] = 0; lrank[b] = 0; }
    __syncthreads();

    int base = blockIdx.x * P1_CHUNK;
    uint2 ed[P1_EPT];
    int   bn[P1_EPT];
    #pragma unroll
    for (int j = 0; j < P1_EPT; ++j) {
        int e = base + tid + j * 256;
        bn[j] = -1;
        if (e < E) {
            int r = ei[e], c = ei[E + e];
            bn[j] = c >> 8;
            ed[j] = make_uint2((unsigned)r | ((unsigned)(c & 255) << 17),
                               __float_as_uint(ew[e]));
            atomicAdd(&hist[bn[j]], 1);
        }
    }
    __syncthreads();
    // exclusive scan of hist[0..NB_MAX) -> loff (thread t owns bins 2t, 2t+1)
    {
        int b0 = 2 * tid, b1 = 2 * tid + 1;
        int h0 = hist[b0], h1 = hist[b1];
        int s = h0 + h1;
        ssc[tid] = s;
        __syncthreads();
        for (int st = 1; st < 256; st <<= 1) {
            int v = (tid >= st) ? ssc[tid - st] : 0;
            __syncthreads();
            ssc[tid] += v;
            __syncthreads();
        }
        int pre = ssc[tid] - s;
        loff[b0] = pre;
        loff[b1] = pre + h0;
    }
    __syncthreads();
    // reserve global space per (block, bin): one far atomic each
    for (int b = tid; b < NB; b += 256) {
        int h = hist[b];
        if (h > 0) gbase[b] = atomicAdd(&binCur[b], h);
    }
    // scatter into LDS, sorted by bin
    #pragma unroll
    for (int j = 0; j < P1_EPT; ++j) {
        if (bn[j] >= 0) {
            int p = loff[bn[j]] + atomicAdd(&lrank[bn[j]], 1);
            sbuf[p] = ed[j];
            sbin[p] = (unsigned short)bn[j];
        }
    }
    __syncthreads();
    // coalesced writeout
    int m = min(E - base, P1_CHUNK);
    for (int i = tid; i < m; i += 256) {
        uint2 u = sbuf[i];
        int b = sbin[i];
        int dst = gbase[b] + (i - loff[b]);
        if (dst < BCAP) binned[(size_t)b * BCAP + dst] = u;
    }
}

// ---- exclusive scan of bin counts (single block) ---------------------------
__global__ void tpn_binscan(const int* __restrict__ binCur, int* __restrict__ binOff,
                            int NB) {
    __shared__ int sh[NB_MAX];
    int t = threadIdx.x;
    int v = (t < NB) ? min(binCur[t], BCAP) : 0;
    sh[t] = v;
    __syncthreads();
    for (int st = 1; st < NB_MAX; st <<= 1) {
        int u = (t >= st) ? sh[t - st] : 0;
        __syncthreads();
        sh[t] += u;
        __syncthreads();
    }
    if (t < NB) binOff[t] = sh[t] - v;
}

// ---- pass 2: per-bin packed CSR build + dis --------------------------------
__global__ void tpn_build(const uint2* __restrict__ binned, const int* __restrict__ binCur,
                          const int* __restrict__ binOff, uint2* __restrict__ packed,
                          int* __restrict__ off, int* __restrict__ cnt,
                          float* __restrict__ dis, int N) {
    __shared__ int   lcnt[256];
    __shared__ int   loff[256];
    __shared__ int   lrank[256];
    __shared__ int   lincl[256];
    __shared__ float ldeg[256];
    int b = blockIdx.x, tid = threadIdx.x;
    int m = min(binCur[b], BCAP);
    const uint2* src = binned + (size_t)b * BCAP;
    lcnt[tid] = 0; lrank[tid] = 0; ldeg[tid] = 0.0f;
    __syncthreads();
    for (int i = tid; i < m; i += 256) {
        uint2 u = src[i];
        int ln = u.x >> 17;
        atomicAdd(&lcnt[ln], 1);
        atomicAdd(&ldeg[ln], __uint_as_float(u.y));
    }
    __syncthreads();
    lincl[tid] = lcnt[tid];
    __syncthreads();
    for (int st = 1; st < 256; st <<= 1) {
        int u = (tid >= st) ? lincl[tid - st] : 0;
        __syncthreads();
        lincl[tid] += u;
        __syncthreads();
    }
    int excl = lincl[tid] - lcnt[tid];
    loff[tid] = excl;
    int node = (b << 8) + tid;
    if (node < N) {
        off[node] = binOff[b] + excl;
        cnt[node] = lcnt[tid];
        float s = ldeg[tid];
        dis[node] = (s > 0.0f) ? rsqrtf(fmaxf(s, 1e-12f)) : 0.0f;
    }
    __syncthreads();
    int gbase = binOff[b];
    for (int i = tid; i < m; i += 256) {
        uint2 u = src[i];
        int ln = u.x >> 17;
        int rk = atomicAdd(&lrank[ln], 1);
        packed[gbase + loff[ln] + rk] = make_uint2(u.x & 0x1FFFF, u.y);
    }
}

// ---- tiled GEMM: Y[n,f] = dis[n] * sum_k X[n,k]*W[k,f]; 64x64 tile ---------
__global__ __launch_bounds__(256, 4)
void tpn_gemm_t(const float* __restrict__ X, const float* __restrict__ W,
                const float* __restrict__ dis, float* __restrict__ Y,
                int N, int K) {
    __shared__ float sX[64][68];
    __shared__ float sW[64][64];
    const int t  = threadIdx.x;
    const int r  = t >> 4;
    const int cc = t & 15;
    const int fg = t & 15;
    const int ng = t >> 4;
    const int nb = blockIdx.x * 64;

    float acc[4][4] = {{0.f}};

    for (int kc = 0; kc < K; kc += 64) {
        __syncthreads();
        #pragma unroll
        for (int p = 0; p < 4; ++p) {
            int n = nb + r + p * 16;
            int ns = (n < N) ? n : (N - 1);
            float4 v = *reinterpret_cast<const float4*>(X + (size_t)ns * K + kc + 4 * cc);
            *reinterpret_cast<float4*>(&sX[r + p * 16][4 * cc]) = v;
        }
        #pragma unroll
        for (int p = 0; p < 4; ++p) {
            int k = kc + r + p * 16;
            float4 v = *reinterpret_cast<const float4*>(W + (size_t)k * 64 + 4 * cc);
            *reinterpret_cast<float4*>(&sW[r + p * 16][4 * cc]) = v;
        }
        __syncthreads();
        #pragma unroll 4
        for (int k = 0; k < 64; ++k) {
            float4 wv = *reinterpret_cast<const float4*>(&sW[k][4 * fg]);
            float x0 = sX[4 * ng + 0][k];
            float x1 = sX[4 * ng + 1][k];
            float x2 = sX[4 * ng + 2][k];
            float x3 = sX[4 * ng + 3][k];
            acc[0][0] = fmaf(x0, wv.x, acc[0][0]);
            acc[0][1] = fmaf(x0, wv.y, acc[0][1]);
            acc[0][2] = fmaf(x0, wv.z, acc[0][2]);
            acc[0][3] = fmaf(x0, wv.w, acc[0][3]);
            acc[1][0] = fmaf(x1, wv.x, acc[1][0]);
            acc[1][1] = fmaf(x1, wv.y, acc[1][1]);
            acc[1][2] = fmaf(x1, wv.z, acc[1][2]);
            acc[1][3] = fmaf(x1, wv.w, acc[1][3]);
            acc[2][0] = fmaf(x2, wv.x, acc[2][0]);
            acc[2][1] = fmaf(x2, wv.y, acc[2][1]);
            acc[2][2] = fmaf(x2, wv.z, acc[2][2]);
            acc[2][3] = fmaf(x2, wv.w, acc[2][3]);
            acc[3][0] = fmaf(x3, wv.x, acc[3][0]);
            acc[3][1] = fmaf(x3, wv.y, acc[3][1]);
            acc[3][2] = fmaf(x3, wv.z, acc[3][2]);
            acc[3][3] = fmaf(x3, wv.w, acc[3][3]);
        }
    }
    #pragma unroll
    for (int i = 0; i < 4; ++i) {
        int n = nb + 4 * ng + i;
        if (n < N) {
            float d = dis[n];
            float4 v = make_float4(acc[i][0] * d, acc[i][1] * d,
                                   acc[i][2] * d, acc[i][3] * d);
            *reinterpret_cast<float4*>(Y + (size_t)n * 64 + 4 * fg) = v;
        }
    }
}

// ---- aggregate: wave/node, 16 lanes x float4, 4 indep gather chains --------
// FUSE_W2: epilogue computes Hout_row = dis[n] * (relu_row @ W2) inline
//          (gemm2 fusion). FUSE_SCORE: sigmoid score gate (layer 2).
template <bool FUSE_SCORE, bool FUSE_W2>
__global__ __launch_bounds__(256)
void tpn_agg(const uint2* __restrict__ packed, const int* __restrict__ off,
             const int* __restrict__ cnt, const float* __restrict__ dis,
             const float* __restrict__ Hin, const float* __restrict__ bias,
             const float* __restrict__ pw, const float* __restrict__ pb,
             const float* __restrict__ W2, float* __restrict__ Hout, int N) {
    int wid = (blockIdx.x * blockDim.x + threadIdx.x) >> 6;
    int lane = threadIdx.x & 63;
    if (wid >= N) return;
    const int eg = lane >> 4;        // edge slot 0..3
    const int fb = (lane & 15) * 4;  // feature base: fb..fb+3
    int start = off[wid], n = cnt[wid];
    const uint2* b = packed + start;
    const float* hp = Hin + fb;
    float dc = dis[wid];             // hoisted, independent load

    float4 A0 = {0.f, 0.f, 0.f, 0.f};
    float4 A1 = {0.f, 0.f, 0.f, 0.f};
    float4 A2 = {0.f, 0.f, 0.f, 0.f};
    float4 A3 = {0.f, 0.f, 0.f, 0.f};
    int j = 0;
    for (; j + 16 <= n; j += 16) {
        uint2 p0 = b[j + eg];
        uint2 p1 = b[j + 4 + eg];
        uint2 p2 = b[j + 8 + eg];
        uint2 p3 = b[j + 12 + eg];
        float4 v0 = *reinterpret_cast<const float4*>(hp + (size_t)p0.x * 64);
        float4 v1 = *reinterpret_cast<const float4*>(hp + (size_t)p1.x * 64);
        float4 v2 = *reinterpret_cast<const float4*>(hp + (size_t)p2.x * 64);
        float4 v3 = *reinterpret_cast<const float4*>(hp + (size_t)p3.x * 64);
        float w0 = __uint_as_float(p0.y);
        float w1 = __uint_as_float(p1.y);
        float w2 = __uint_as_float(p2.y);
        float w3 = __uint_as_float(p3.y);
        A0.x = fmaf(w0, v0.x, A0.x); A0.y = fmaf(w0, v0.y, A0.y);
        A0.z = fmaf(w0, v0.z, A0.z); A0.w = fmaf(w0, v0.w, A0.w);
        A1.x = fmaf(w1, v1.x, A1.x); A1.y = fmaf(w1, v1.y, A1.y);
        A1.z = fmaf(w1, v1.z, A1.z); A1.w = fmaf(w1, v1.w, A1.w);
        A2.x = fmaf(w2, v2.x, A2.x); A2.y = fmaf(w2, v2.y, A2.y);
        A2.z = fmaf(w2, v2.z, A2.z); A2.w = fmaf(w2, v2.w, A2.w);
        A3.x = fmaf(w3, v3.x, A3.x); A3.y = fmaf(w3, v3.y, A3.y);
        A3.z = fmaf(w3, v3.z, A3.z); A3.w = fmaf(w3, v3.w, A3.w);
    }
    for (; j + 8 <= n; j += 8) {
        uint2 p0 = b[j + eg];
        uint2 p1 = b[j + 4 + eg];
        float4 v0 = *reinterpret_cast<const float4*>(hp + (size_t)p0.x * 64);
        float4 v1 = *reinterpret_cast<const float4*>(hp + (size_t)p1.x * 64);
        float w0 = __uint_as_float(p0.y);
        float w1 = __uint_as_float(p1.y);
        A0.x = fmaf(w0, v0.x, A0.x); A0.y = fmaf(w0, v0.y, A0.y);
        A0.z = fmaf(w0, v0.z, A0.z); A0.w = fmaf(w0, v0.w, A0.w);
        A1.x = fmaf(w1, v1.x, A1.x); A1.y = fmaf(w1, v1.y, A1.y);
        A1.z = fmaf(w1, v1.z, A1.z); A1.w = fmaf(w1, v1.w, A1.w);
    }
    for (; j < n; j += 4) {
        int idx = j + eg;
        uint2 p = (idx < n) ? b[idx] : make_uint2(0u, 0u);  // w=0 for pad lanes
        float4 v = *reinterpret_cast<const float4*>(hp + (size_t)p.x * 64);
        float w = __uint_as_float(p.y);
        A0.x = fmaf(w, v.x, A0.x); A0.y = fmaf(w, v.y, A0.y);
        A0.z = fmaf(w, v.z, A0.z); A0.w = fmaf(w, v.w, A0.w);
    }
    float4 acc;
    acc.x = (A0.x + A1.x) + (A2.x + A3.x);
    acc.y = (A0.y + A1.y) + (A2.y + A3.y);
    acc.z = (A0.z + A1.z) + (A2.z + A3.z);
    acc.w = (A0.w + A1.w) + (A2.w + A3.w);
    // fold the 4 edge slots (lanes ^16, ^32) -> ALL lanes hold the folded row
    acc.x += __shfl_xor(acc.x, 16); acc.x += __shfl_xor(acc.x, 32);
    acc.y += __shfl_xor(acc.y, 16); acc.y += __shfl_xor(acc.y, 32);
    acc.z += __shfl_xor(acc.z, 16); acc.z += __shfl_xor(acc.z, 32);
    acc.w += __shfl_xor(acc.w, 16); acc.w += __shfl_xor(acc.w, 32);

    const float4 bv = *reinterpret_cast<const float4*>(bias + fb);
    float4 h;
    h.x = fmaxf(fmaf(acc.x, dc, bv.x), 0.0f);
    h.y = fmaxf(fmaf(acc.y, dc, bv.y), 0.0f);
    h.z = fmaxf(fmaf(acc.z, dc, bv.z), 0.0f);
    h.w = fmaxf(fmaf(acc.w, dc, bv.w), 0.0f);
    if (FUSE_SCORE) {
        const float4 pv = *reinterpret_cast<const float4*>(pw + fb);
        float t = h.x * pv.x + h.y * pv.y + h.z * pv.z + h.w * pv.w;
        #pragma unroll
        for (int m = 1; m <= 8; m <<= 1) t += __shfl_xor(t, m);  // 16-lane group
        float s = 1.0f / (1.0f + expf(-(t + pb[0])));
        h.x *= s; h.y *= s; h.z *= s; h.w *= s;
    }
    if (FUSE_W2) {
        // hB row is replicated across all 4 groups; lane q (0..15) holds
        // hB[4q..4q+3]. Compute out[lane] = dis * sum_k hB[k]*W2[k][lane].
        float a2 = 0.0f;
        #pragma unroll
        for (int q = 0; q < 16; ++q) {
            float b0 = __shfl(h.x, q);
            float b1 = __shfl(h.y, q);
            float b2 = __shfl(h.z, q);
            float b3 = __shfl(h.w, q);
            a2 = fmaf(b0, W2[(4 * q + 0) * 64 + lane], a2);
            a2 = fmaf(b1, W2[(4 * q + 1) * 64 + lane], a2);
            a2 = fmaf(b2, W2[(4 * q + 2) * 64 + lane], a2);
            a2 = fmaf(b3, W2[(4 * q + 3) * 64 + lane], a2);
        }
        Hout[(size_t)wid * 64 + lane] = dc * a2;   // coalesced 4B/lane
    } else {
        if (eg == 0)
            *reinterpret_cast<float4*>(Hout + (size_t)wid * 64 + fb) = h;
    }
}

// ---- per-graph max || mean pooling (batch sorted) --------------------------
__global__ void tpn_pool(const float* __restrict__ Hs, const int* __restrict__ batch,
                         int N, float* __restrict__ Gf) {
    int g = blockIdx.x;
    int s, e;
    {
        int lo = 0, hi = N;
        while (lo < hi) { int mid = (lo + hi) >> 1; if (batch[mid] < g) lo = mid + 1; else hi = mid; }
        s = lo;
        lo = 0; hi = N;
        while (lo < hi) { int mid = (lo + hi) >> 1; if (batch[mid] < g + 1) lo = mid + 1; else hi = mid; }
        e = lo;
    }
    int lane = threadIdx.x & 63;
    int w = threadIdx.x >> 6;  // 0..3
    float mx = -3.4e38f, sm = 0.0f;
    for (int i = s + w; i < e; i += 4) {
        float v = Hs[(size_t)i * 64 + lane];
        mx = fmaxf(mx, v);
        sm += v;
    }
    __shared__ float shm[4][64], shs[4][64];
    shm[w][lane] = mx; shs[w][lane] = sm;
    __syncthreads();
    if (w == 0) {
        mx = fmaxf(fmaxf(shm[0][lane], shm[1][lane]), fmaxf(shm[2][lane], shm[3][lane]));
        sm = shs[0][lane] + shs[1][lane] + shs[2][lane] + shs[3][lane];
        float c = (float)(e - s);
        float inv = 1.0f / fmaxf(c, 1.0f);
        Gf[g * 128 + lane]      = mx;
        Gf[g * 128 + 64 + lane] = sm * inv;
    }
}

// ---- final MLP: out = relu(G @ lw1 + lb1) @ lw2 + lb2 ----------------------
__global__ void tpn_mlp(const float* __restrict__ Gf, const float* __restrict__ lw1,
                        const float* __restrict__ lb1, const float* __restrict__ lw2,
                        const float* __restrict__ lb2, float* __restrict__ out,
                        int G, int C) {
    int wid = (blockIdx.x * blockDim.x + threadIdx.x) >> 6;
    int lane = threadIdx.x & 63;
    if (wid >= G) return;
    const float* gr = Gf + (size_t)wid * 128;
    float acc = lb1[lane];
    for (int k = 0; k < 128; k += 4) {
        float4 gv = *reinterpret_cast<const float4*>(gr + k);
        acc = fmaf(gv.x, lw1[(k + 0) * 64 + lane], acc);
        acc = fmaf(gv.y, lw1[(k + 1) * 64 + lane], acc);
        acc = fmaf(gv.z, lw1[(k + 2) * 64 + lane], acc);
        acc = fmaf(gv.w, lw1[(k + 3) * 64 + lane], acc);
    }
    float t = fmaxf(acc, 0.0f);
    for (int c = 0; c < C; ++c) {
        float v = t * lw2[lane * C + c];
        #pragma unroll
        for (int m = 32; m > 0; m >>= 1) v += __shfl_xor(v, m);
        if (lane == 0) out[wid * C + c] = v + lb2[c];
    }
}

// ---------------------------------------------------------------------------
extern "C" void kernel_launch(void* const* d_in, const int* in_sizes, int n_in,
                              void* d_out, int out_size, void* d_ws, size_t ws_size,
                              hipStream_t stream) {
    const float* x   = (const float*)d_in[0];
    const int*   ei  = (const int*)  d_in[1];
    const float* ew  = (const float*)d_in[2];
    const int*   bat = (const int*)  d_in[3];
    const float* W1  = (const float*)d_in[5];
    const float* b1  = (const float*)d_in[6];
    const float* W2  = (const float*)d_in[7];
    const float* b2  = (const float*)d_in[8];
    const float* pw  = (const float*)d_in[9];
    const float* pb  = (const float*)d_in[10];
    const float* lw1 = (const float*)d_in[11];
    const float* lb1 = (const float*)d_in[12];
    const float* lw2 = (const float*)d_in[13];
    const float* lb2 = (const float*)d_in[14];
    float* out = (float*)d_out;

    const int N  = in_sizes[3];
    const int E  = in_sizes[2];
    const int IN = in_sizes[0] / N;   // 128
    const int C  = in_sizes[14];      // 2
    const int G  = out_size / C;      // 128
    const int NB = (N + 255) >> 8;    // bins of 256 nodes

    // ---- workspace layout ----
    char* ws = (char*)d_ws;
    size_t o = 0;
    auto alloc = [&](size_t bytes) { void* p = ws + o; o = (o + bytes + 255) & ~(size_t)255; return p; };
    int*   off    = (int*)  alloc((size_t)N * 4);
    int*   cnt    = (int*)  alloc((size_t)N * 4);
    float* dis    = (float*)alloc((size_t)N * 4);
    int*   binCur = (int*)  alloc((size_t)NB_MAX * 4);
    int*   binOff = (int*)  alloc((size_t)NB_MAX * 4);
    float* Gf     = (float*)alloc((size_t)G * 128 * 4);
    uint2* packed = (uint2*)alloc((size_t)E * 8);
    float* hA     = (float*)alloc((size_t)N * 64 * 4);
    float* hB     = (float*)alloc((size_t)N * 64 * 4);
    // binned is dead after tpn_build -> alias it over hA/hB
    uint2* binned = (uint2*)hA;
    (void)n_in; (void)ws_size;

    (void)hipMemsetAsync(binCur, 0, (size_t)NB_MAX * 4, stream);

    const int p1b   = (E + P1_CHUNK - 1) / P1_CHUNK;
    const int ggrid = (N + 63) / 64;                        // gemm tiles
    const int agrid = (N * 64 + TPN_BLK - 1) / TPN_BLK;     // wave per node

    // CSR build: bin (LDS sort, coalesced) -> scan -> build
    tpn_bin<<<p1b, TPN_BLK, 0, stream>>>(ei, ew, binCur, binned, E, NB);
    tpn_binscan<<<1, NB_MAX, 0, stream>>>(binCur, binOff, NB);
    tpn_build<<<NB, 256, 0, stream>>>(binned, binCur, binOff, packed, off, cnt, dis, N);

    // layer 1 (+fused gemm2): hA = dis*(x@W1); hB = dis*(relu(dis*agg(hA)+b1)@W2)
    tpn_gemm_t<<<ggrid, 256, 0, stream>>>(x, W1, dis, hA, N, IN);
    tpn_agg<false, true><<<agrid, TPN_BLK, 0, stream>>>(packed, off, cnt, dis, hA,
                                                        b1, pw, pb, W2, hB, N);

    // layer 2: hA = score-gated relu(dis*agg(hB) + b2)
    tpn_agg<true, false><<<agrid, TPN_BLK, 0, stream>>>(packed, off, cnt, dis, hB,
                                                        b2, pw, pb, W2, hA, N);

    // pooling + MLP head
    tpn_pool<<<G, TPN_BLK, 0, stream>>>(hA, bat, N, Gf);
    tpn_mlp<<<(G * 64 + TPN_BLK - 1) / TPN_BLK, TPN_BLK, 0, stream>>>(Gf, lw1, lb1, lw2, lb2, out, G, C);
}

// Round 17
// 361.290 us; speedup vs baseline: 4.6802x; 1.1329x over previous
//
#include <hip/hip_runtime.h>
#include <hip/hip_fp16.h>
#include <math.h>

// ---------------------------------------------------------------------------
// TopoPoolNet: GCN(128->64) -> GCN(64->64) -> sigmoid score gate ->
//              per-graph max||mean pool -> MLP(128->64->2)
//
// Round-15/16: agg is HBM-random-access bound (FETCH invariant 361MB at ~3.5
// TB/s across 7 variants). Cut BYTES instead of reordering accesses:
// activations (hA, hB, agg2 out) stored as fp16, all math in fp32.
// Row-gather 256B -> 128B per edge; Hin 25.6 -> 12.8MB (L2-friendlier).
// (R16: __floats2half2_rn takes (float,float) on ROCm, not float2.)
// ---------------------------------------------------------------------------

#define TPN_BLK 256
#define P1_EPT  16                   // edges per thread in bin pass
#define P1_CHUNK (TPN_BLK * P1_EPT)  // 4096 edges per block
#define NB_MAX  512
#define BCAP    12288                // per-bin capacity (mean ~8184)

static __device__ __forceinline__ float4 h4_to_f4(uint2 u) {
    __half2 a = *reinterpret_cast<__half2*>(&u.x);
    __half2 b = *reinterpret_cast<__half2*>(&u.y);
    float2 fa = __half22float2(a), fb = __half22float2(b);
    return make_float4(fa.x, fa.y, fb.x, fb.y);
}
static __device__ __forceinline__ uint2 f4_to_h4(float4 v) {
    __half2 a = __floats2half2_rn(v.x, v.y);
    __half2 b = __floats2half2_rn(v.z, v.w);
    uint2 u;
    u.x = *reinterpret_cast<unsigned*>(&a);
    u.y = *reinterpret_cast<unsigned*>(&b);
    return u;
}

// ---- pass 1: block-level counting sort by bin (col>>8), coalesced out -----
__global__ __launch_bounds__(256)
void tpn_bin(const int* __restrict__ ei, const float* __restrict__ ew,
             int* __restrict__ binCur, uint2* __restrict__ binned,
             int E, int NB) {
    __shared__ uint2          sbuf[P1_CHUNK];      // 32 KB
    __shared__ unsigned short sbin[P1_CHUNK];      // 8 KB
    __shared__ int hist[NB_MAX];
    __shared__ int loff[NB_MAX];
    __shared__ int lrank[NB_MAX];
    __shared__ int gbase[NB_MAX];
    __shared__ int ssc[256];

    int tid = threadIdx.x;
    for (int b = tid; b < NB_MAX; b += 256) { hist[b] = 0; lrank[b] = 0; }
    __syncthreads();

    int base = blockIdx.x * P1_CHUNK;
    uint2 ed[P1_EPT];
    int   bn[P1_EPT];
    #pragma unroll
    for (int j = 0; j < P1_EPT; ++j) {
        int e = base + tid + j * 256;
        bn[j] = -1;
        if (e < E) {
            int r = ei[e], c = ei[E + e];
            bn[j] = c >> 8;
            ed[j] = make_uint2((unsigned)r | ((unsigned)(c & 255) << 17),
                               __float_as_uint(ew[e]));
            atomicAdd(&hist[bn[j]], 1);
        }
    }
    __syncthreads();
    {
        int b0 = 2 * tid, b1 = 2 * tid + 1;
        int h0 = hist[b0], h1 = hist[b1];
        int s = h0 + h1;
        ssc[tid] = s;
        __syncthreads();
        for (int st = 1; st < 256; st <<= 1) {
            int v = (tid >= st) ? ssc[tid - st] : 0;
            __syncthreads();
            ssc[tid] += v;
            __syncthreads();
        }
        int pre = ssc[tid] - s;
        loff[b0] = pre;
        loff[b1] = pre + h0;
    }
    __syncthreads();
    for (int b = tid; b < NB; b += 256) {
        int h = hist[b];
        if (h > 0) gbase[b] = atomicAdd(&binCur[b], h);
    }
    #pragma unroll
    for (int j = 0; j < P1_EPT; ++j) {
        if (bn[j] >= 0) {
            int p = loff[bn[j]] + atomicAdd(&lrank[bn[j]], 1);
            sbuf[p] = ed[j];
            sbin[p] = (unsigned short)bn[j];
        }
    }
    __syncthreads();
    int m = min(E - base, P1_CHUNK);
    for (int i = tid; i < m; i += 256) {
        uint2 u = sbuf[i];
        int b = sbin[i];
        int dst = gbase[b] + (i - loff[b]);
        if (dst < BCAP) binned[(size_t)b * BCAP + dst] = u;
    }
}

// ---- exclusive scan of bin counts (single block) ---------------------------
__global__ void tpn_binscan(const int* __restrict__ binCur, int* __restrict__ binOff,
                            int NB) {
    __shared__ int sh[NB_MAX];
    int t = threadIdx.x;
    int v = (t < NB) ? min(binCur[t], BCAP) : 0;
    sh[t] = v;
    __syncthreads();
    for (int st = 1; st < NB_MAX; st <<= 1) {
        int u = (t >= st) ? sh[t - st] : 0;
        __syncthreads();
        sh[t] += u;
        __syncthreads();
    }
    if (t < NB) binOff[t] = sh[t] - v;
}

// ---- pass 2: per-bin packed CSR build + dis --------------------------------
__global__ void tpn_build(const uint2* __restrict__ binned, const int* __restrict__ binCur,
                          const int* __restrict__ binOff, uint2* __restrict__ packed,
                          int* __restrict__ off, int* __restrict__ cnt,
                          float* __restrict__ dis, int N) {
    __shared__ int   lcnt[256];
    __shared__ int   loff[256];
    __shared__ int   lrank[256];
    __shared__ int   lincl[256];
    __shared__ float ldeg[256];
    int b = blockIdx.x, tid = threadIdx.x;
    int m = min(binCur[b], BCAP);
    const uint2* src = binned + (size_t)b * BCAP;
    lcnt[tid] = 0; lrank[tid] = 0; ldeg[tid] = 0.0f;
    __syncthreads();
    for (int i = tid; i < m; i += 256) {
        uint2 u = src[i];
        int ln = u.x >> 17;
        atomicAdd(&lcnt[ln], 1);
        atomicAdd(&ldeg[ln], __uint_as_float(u.y));
    }
    __syncthreads();
    lincl[tid] = lcnt[tid];
    __syncthreads();
    for (int st = 1; st < 256; st <<= 1) {
        int u = (tid >= st) ? lincl[tid - st] : 0;
        __syncthreads();
        lincl[tid] += u;
        __syncthreads();
    }
    int excl = lincl[tid] - lcnt[tid];
    loff[tid] = excl;
    int node = (b << 8) + tid;
    if (node < N) {
        off[node] = binOff[b] + excl;
        cnt[node] = lcnt[tid];
        float s = ldeg[tid];
        dis[node] = (s > 0.0f) ? rsqrtf(fmaxf(s, 1e-12f)) : 0.0f;
    }
    __syncthreads();
    int gbase = binOff[b];
    for (int i = tid; i < m; i += 256) {
        uint2 u = src[i];
        int ln = u.x >> 17;
        int rk = atomicAdd(&lrank[ln], 1);
        packed[gbase + loff[ln] + rk] = make_uint2(u.x & 0x1FFFF, u.y);
    }
}

// ---- tiled GEMM: Y[n,f] = fp16(dis[n] * sum_k X[n,k]*W[k,f]); 64x64 tile ---
__global__ __launch_bounds__(256, 4)
void tpn_gemm_t(const float* __restrict__ X, const float* __restrict__ W,
                const float* __restrict__ dis, __half* __restrict__ Y,
                int N, int K) {
    __shared__ float sX[64][68];
    __shared__ float sW[64][64];
    const int t  = threadIdx.x;
    const int r  = t >> 4;
    const int cc = t & 15;
    const int fg = t & 15;
    const int ng = t >> 4;
    const int nb = blockIdx.x * 64;

    float acc[4][4] = {{0.f}};

    for (int kc = 0; kc < K; kc += 64) {
        __syncthreads();
        #pragma unroll
        for (int p = 0; p < 4; ++p) {
            int n = nb + r + p * 16;
            int ns = (n < N) ? n : (N - 1);
            float4 v = *reinterpret_cast<const float4*>(X + (size_t)ns * K + kc + 4 * cc);
            *reinterpret_cast<float4*>(&sX[r + p * 16][4 * cc]) = v;
        }
        #pragma unroll
        for (int p = 0; p < 4; ++p) {
            int k = kc + r + p * 16;
            float4 v = *reinterpret_cast<const float4*>(W + (size_t)k * 64 + 4 * cc);
            *reinterpret_cast<float4*>(&sW[r + p * 16][4 * cc]) = v;
        }
        __syncthreads();
        #pragma unroll 4
        for (int k = 0; k < 64; ++k) {
            float4 wv = *reinterpret_cast<const float4*>(&sW[k][4 * fg]);
            float x0 = sX[4 * ng + 0][k];
            float x1 = sX[4 * ng + 1][k];
            float x2 = sX[4 * ng + 2][k];
            float x3 = sX[4 * ng + 3][k];
            acc[0][0] = fmaf(x0, wv.x, acc[0][0]);
            acc[0][1] = fmaf(x0, wv.y, acc[0][1]);
            acc[0][2] = fmaf(x0, wv.z, acc[0][2]);
            acc[0][3] = fmaf(x0, wv.w, acc[0][3]);
            acc[1][0] = fmaf(x1, wv.x, acc[1][0]);
            acc[1][1] = fmaf(x1, wv.y, acc[1][1]);
            acc[1][2] = fmaf(x1, wv.z, acc[1][2]);
            acc[1][3] = fmaf(x1, wv.w, acc[1][3]);
            acc[2][0] = fmaf(x2, wv.x, acc[2][0]);
            acc[2][1] = fmaf(x2, wv.y, acc[2][1]);
            acc[2][2] = fmaf(x2, wv.z, acc[2][2]);
            acc[2][3] = fmaf(x2, wv.w, acc[2][3]);
            acc[3][0] = fmaf(x3, wv.x, acc[3][0]);
            acc[3][1] = fmaf(x3, wv.y, acc[3][1]);
            acc[3][2] = fmaf(x3, wv.z, acc[3][2]);
            acc[3][3] = fmaf(x3, wv.w, acc[3][3]);
        }
    }
    #pragma unroll
    for (int i = 0; i < 4; ++i) {
        int n = nb + 4 * ng + i;
        if (n < N) {
            float d = dis[n];
            float4 v = make_float4(acc[i][0] * d, acc[i][1] * d,
                                   acc[i][2] * d, acc[i][3] * d);
            *reinterpret_cast<uint2*>(Y + (size_t)n * 64 + 4 * fg) = f4_to_h4(v);
        }
    }
}

// ---- aggregate: wave/node, 16 lanes x half4, 4 indep gather chains ---------
// FUSE_W2: epilogue computes Hout_row = fp16(dis[n] * (relu_row @ W2)) inline.
// FUSE_SCORE: sigmoid score gate (layer 2).
template <bool FUSE_SCORE, bool FUSE_W2>
__global__ __launch_bounds__(256)
void tpn_agg(const uint2* __restrict__ packed, const int* __restrict__ off,
             const int* __restrict__ cnt, const float* __restrict__ dis,
             const __half* __restrict__ Hin, const float* __restrict__ bias,
             const float* __restrict__ pw, const float* __restrict__ pb,
             const float* __restrict__ W2, __half* __restrict__ Hout, int N) {
    int wid = (blockIdx.x * blockDim.x + threadIdx.x) >> 6;
    int lane = threadIdx.x & 63;
    if (wid >= N) return;
    const int eg = lane >> 4;        // edge slot 0..3
    const int fb = (lane & 15) * 4;  // feature base: fb..fb+3
    int start = off[wid], n = cnt[wid];
    const uint2* b = packed + start;
    const __half* hp = Hin + fb;
    float dc = dis[wid];

    float4 A0 = {0.f, 0.f, 0.f, 0.f};
    float4 A1 = {0.f, 0.f, 0.f, 0.f};
    float4 A2 = {0.f, 0.f, 0.f, 0.f};
    float4 A3 = {0.f, 0.f, 0.f, 0.f};
    int j = 0;
    for (; j + 16 <= n; j += 16) {
        uint2 p0 = b[j + eg];
        uint2 p1 = b[j + 4 + eg];
        uint2 p2 = b[j + 8 + eg];
        uint2 p3 = b[j + 12 + eg];
        uint2 r0 = *reinterpret_cast<const uint2*>(hp + (size_t)p0.x * 64);
        uint2 r1 = *reinterpret_cast<const uint2*>(hp + (size_t)p1.x * 64);
        uint2 r2 = *reinterpret_cast<const uint2*>(hp + (size_t)p2.x * 64);
        uint2 r3 = *reinterpret_cast<const uint2*>(hp + (size_t)p3.x * 64);
        float4 v0 = h4_to_f4(r0);
        float4 v1 = h4_to_f4(r1);
        float4 v2 = h4_to_f4(r2);
        float4 v3 = h4_to_f4(r3);
        float w0 = __uint_as_float(p0.y);
        float w1 = __uint_as_float(p1.y);
        float w2 = __uint_as_float(p2.y);
        float w3 = __uint_as_float(p3.y);
        A0.x = fmaf(w0, v0.x, A0.x); A0.y = fmaf(w0, v0.y, A0.y);
        A0.z = fmaf(w0, v0.z, A0.z); A0.w = fmaf(w0, v0.w, A0.w);
        A1.x = fmaf(w1, v1.x, A1.x); A1.y = fmaf(w1, v1.y, A1.y);
        A1.z = fmaf(w1, v1.z, A1.z); A1.w = fmaf(w1, v1.w, A1.w);
        A2.x = fmaf(w2, v2.x, A2.x); A2.y = fmaf(w2, v2.y, A2.y);
        A2.z = fmaf(w2, v2.z, A2.z); A2.w = fmaf(w2, v2.w, A2.w);
        A3.x = fmaf(w3, v3.x, A3.x); A3.y = fmaf(w3, v3.y, A3.y);
        A3.z = fmaf(w3, v3.z, A3.z); A3.w = fmaf(w3, v3.w, A3.w);
    }
    for (; j + 8 <= n; j += 8) {
        uint2 p0 = b[j + eg];
        uint2 p1 = b[j + 4 + eg];
        uint2 r0 = *reinterpret_cast<const uint2*>(hp + (size_t)p0.x * 64);
        uint2 r1 = *reinterpret_cast<const uint2*>(hp + (size_t)p1.x * 64);
        float4 v0 = h4_to_f4(r0);
        float4 v1 = h4_to_f4(r1);
        float w0 = __uint_as_float(p0.y);
        float w1 = __uint_as_float(p1.y);
        A0.x = fmaf(w0, v0.x, A0.x); A0.y = fmaf(w0, v0.y, A0.y);
        A0.z = fmaf(w0, v0.z, A0.z); A0.w = fmaf(w0, v0.w, A0.w);
        A1.x = fmaf(w1, v1.x, A1.x); A1.y = fmaf(w1, v1.y, A1.y);
        A1.z = fmaf(w1, v1.z, A1.z); A1.w = fmaf(w1, v1.w, A1.w);
    }
    for (; j < n; j += 4) {
        int idx = j + eg;
        uint2 p = (idx < n) ? b[idx] : make_uint2(0u, 0u);  // w=0 for pad lanes
        uint2 r = *reinterpret_cast<const uint2*>(hp + (size_t)p.x * 64);
        float4 v = h4_to_f4(r);
        float w = __uint_as_float(p.y);
        A0.x = fmaf(w, v.x, A0.x); A0.y = fmaf(w, v.y, A0.y);
        A0.z = fmaf(w, v.z, A0.z); A0.w = fmaf(w, v.w, A0.w);
    }
    float4 acc;
    acc.x = (A0.x + A1.x) + (A2.x + A3.x);
    acc.y = (A0.y + A1.y) + (A2.y + A3.y);
    acc.z = (A0.z + A1.z) + (A2.z + A3.z);
    acc.w = (A0.w + A1.w) + (A2.w + A3.w);
    // fold the 4 edge slots (lanes ^16, ^32) -> ALL lanes hold the folded row
    acc.x += __shfl_xor(acc.x, 16); acc.x += __shfl_xor(acc.x, 32);
    acc.y += __shfl_xor(acc.y, 16); acc.y += __shfl_xor(acc.y, 32);
    acc.z += __shfl_xor(acc.z, 16); acc.z += __shfl_xor(acc.z, 32);
    acc.w += __shfl_xor(acc.w, 16); acc.w += __shfl_xor(acc.w, 32);

    const float4 bv = *reinterpret_cast<const float4*>(bias + fb);
    float4 h;
    h.x = fmaxf(fmaf(acc.x, dc, bv.x), 0.0f);
    h.y = fmaxf(fmaf(acc.y, dc, bv.y), 0.0f);
    h.z = fmaxf(fmaf(acc.z, dc, bv.z), 0.0f);
    h.w = fmaxf(fmaf(acc.w, dc, bv.w), 0.0f);
    if (FUSE_SCORE) {
        const float4 pv = *reinterpret_cast<const float4*>(pw + fb);
        float t = h.x * pv.x + h.y * pv.y + h.z * pv.z + h.w * pv.w;
        #pragma unroll
        for (int m = 1; m <= 8; m <<= 1) t += __shfl_xor(t, m);  // 16-lane group
        float s = 1.0f / (1.0f + expf(-(t + pb[0])));
        h.x *= s; h.y *= s; h.z *= s; h.w *= s;
    }
    if (FUSE_W2) {
        // lane q (0..15) holds hB[4q..4q+3]; out[lane] = dis*sum_k hB[k]*W2[k][lane]
        float a2 = 0.0f;
        #pragma unroll
        for (int q = 0; q < 16; ++q) {
            float b0 = __shfl(h.x, q);
            float b1 = __shfl(h.y, q);
            float b2 = __shfl(h.z, q);
            float b3 = __shfl(h.w, q);
            a2 = fmaf(b0, W2[(4 * q + 0) * 64 + lane], a2);
            a2 = fmaf(b1, W2[(4 * q + 1) * 64 + lane], a2);
            a2 = fmaf(b2, W2[(4 * q + 2) * 64 + lane], a2);
            a2 = fmaf(b3, W2[(4 * q + 3) * 64 + lane], a2);
        }
        Hout[(size_t)wid * 64 + lane] = __float2half(dc * a2);  // coalesced 2B/lane
    } else {
        if (eg == 0)
            *reinterpret_cast<uint2*>(Hout + (size_t)wid * 64 + fb) = f4_to_h4(h);
    }
}

// ---- per-graph max || mean pooling (batch sorted, fp16 input) --------------
__global__ void tpn_pool(const __half* __restrict__ Hs, const int* __restrict__ batch,
                         int N, float* __restrict__ Gf) {
    int g = blockIdx.x;
    int s, e;
    {
        int lo = 0, hi = N;
        while (lo < hi) { int mid = (lo + hi) >> 1; if (batch[mid] < g) lo = mid + 1; else hi = mid; }
        s = lo;
        lo = 0; hi = N;
        while (lo < hi) { int mid = (lo + hi) >> 1; if (batch[mid] < g + 1) lo = mid + 1; else hi = mid; }
        e = lo;
    }
    int lane = threadIdx.x & 63;
    int w = threadIdx.x >> 6;  // 0..3
    float mx = -3.4e38f, sm = 0.0f;
    for (int i = s + w; i < e; i += 4) {
        float v = __half2float(Hs[(size_t)i * 64 + lane]);
        mx = fmaxf(mx, v);
        sm += v;
    }
    __shared__ float shm[4][64], shs[4][64];
    shm[w][lane] = mx; shs[w][lane] = sm;
    __syncthreads();
    if (w == 0) {
        mx = fmaxf(fmaxf(shm[0][lane], shm[1][lane]), fmaxf(shm[2][lane], shm[3][lane]));
        sm = shs[0][lane] + shs[1][lane] + shs[2][lane] + shs[3][lane];
        float c = (float)(e - s);
        float inv = 1.0f / fmaxf(c, 1.0f);
        Gf[g * 128 + lane]      = mx;
        Gf[g * 128 + 64 + lane] = sm * inv;
    }
}

// ---- final MLP: out = relu(G @ lw1 + lb1) @ lw2 + lb2 ----------------------
__global__ void tpn_mlp(const float* __restrict__ Gf, const float* __restrict__ lw1,
                        const float* __restrict__ lb1, const float* __restrict__ lw2,
                        const float* __restrict__ lb2, float* __restrict__ out,
                        int G, int C) {
    int wid = (blockIdx.x * blockDim.x + threadIdx.x) >> 6;
    int lane = threadIdx.x & 63;
    if (wid >= G) return;
    const float* gr = Gf + (size_t)wid * 128;
    float acc = lb1[lane];
    for (int k = 0; k < 128; k += 4) {
        float4 gv = *reinterpret_cast<const float4*>(gr + k);
        acc = fmaf(gv.x, lw1[(k + 0) * 64 + lane], acc);
        acc = fmaf(gv.y, lw1[(k + 1) * 64 + lane], acc);
        acc = fmaf(gv.z, lw1[(k + 2) * 64 + lane], acc);
        acc = fmaf(gv.w, lw1[(k + 3) * 64 + lane], acc);
    }
    float t = fmaxf(acc, 0.0f);
    for (int c = 0; c < C; ++c) {
        float v = t * lw2[lane * C + c];
        #pragma unroll
        for (int m = 32; m > 0; m >>= 1) v += __shfl_xor(v, m);
        if (lane == 0) out[wid * C + c] = v + lb2[c];
    }
}

// ---------------------------------------------------------------------------
extern "C" void kernel_launch(void* const* d_in, const int* in_sizes, int n_in,
                              void* d_out, int out_size, void* d_ws, size_t ws_size,
                              hipStream_t stream) {
    const float* x   = (const float*)d_in[0];
    const int*   ei  = (const int*)  d_in[1];
    const float* ew  = (const float*)d_in[2];
    const int*   bat = (const int*)  d_in[3];
    const float* W1  = (const float*)d_in[5];
    const float* b1  = (const float*)d_in[6];
    const float* W2  = (const float*)d_in[7];
    const float* b2  = (const float*)d_in[8];
    const float* pw  = (const float*)d_in[9];
    const float* pb  = (const float*)d_in[10];
    const float* lw1 = (const float*)d_in[11];
    const float* lb1 = (const float*)d_in[12];
    const float* lw2 = (const float*)d_in[13];
    const float* lb2 = (const float*)d_in[14];
    float* out = (float*)d_out;

    const int N  = in_sizes[3];
    const int E  = in_sizes[2];
    const int IN = in_sizes[0] / N;   // 128
    const int C  = in_sizes[14];      // 2
    const int G  = out_size / C;      // 128
    const int NB = (N + 255) >> 8;    // bins of 256 nodes

    // ---- workspace layout ----
    char* ws = (char*)d_ws;
    size_t o = 0;
    auto alloc = [&](size_t bytes) { void* p = ws + o; o = (o + bytes + 255) & ~(size_t)255; return p; };
    int*   off    = (int*)  alloc((size_t)N * 4);
    int*   cnt    = (int*)  alloc((size_t)N * 4);
    float* dis    = (float*)alloc((size_t)N * 4);
    int*   binCur = (int*)  alloc((size_t)NB_MAX * 4);
    int*   binOff = (int*)  alloc((size_t)NB_MAX * 4);
    float* Gf     = (float*)alloc((size_t)G * 128 * 4);
    uint2* packed = (uint2*)alloc((size_t)E * 8);
    // shared region: binned (NB*BCAP*8 = 38.4MB) overlays hA+hB (25.6MB);
    // binned dead after tpn_build.
    size_t binned_bytes = (size_t)NB * BCAP * 8;
    size_t act_bytes    = (size_t)N * 64 * 2 * 2;
    char*  region = (char*)alloc(binned_bytes > act_bytes ? binned_bytes : act_bytes);
    uint2* binned = (uint2*)region;
    __half* hA = (__half*)region;
    __half* hB = (__half*)(region + (size_t)N * 64 * 2);
    (void)n_in; (void)ws_size;

    (void)hipMemsetAsync(binCur, 0, (size_t)NB_MAX * 4, stream);

    const int p1b   = (E + P1_CHUNK - 1) / P1_CHUNK;
    const int ggrid = (N + 63) / 64;                        // gemm tiles
    const int agrid = (N * 64 + TPN_BLK - 1) / TPN_BLK;     // wave per node

    // CSR build: bin (LDS sort, coalesced) -> scan -> build
    tpn_bin<<<p1b, TPN_BLK, 0, stream>>>(ei, ew, binCur, binned, E, NB);
    tpn_binscan<<<1, NB_MAX, 0, stream>>>(binCur, binOff, NB);
    tpn_build<<<NB, 256, 0, stream>>>(binned, binCur, binOff, packed, off, cnt, dis, N);

    // layer 1 (+fused gemm2): hA = fp16(dis*(x@W1));
    //                         hB = fp16(dis*(relu(dis*agg(hA)+b1)@W2))
    tpn_gemm_t<<<ggrid, 256, 0, stream>>>(x, W1, dis, hA, N, IN);
    tpn_agg<false, true><<<agrid, TPN_BLK, 0, stream>>>(packed, off, cnt, dis, hA,
                                                        b1, pw, pb, W2, hB, N);

    // layer 2: hA = fp16(score-gated relu(dis*agg(hB) + b2))
    tpn_agg<true, false><<<agrid, TPN_BLK, 0, stream>>>(packed, off, cnt, dis, hB,
                                                        b2, pw, pb, W2, hA, N);

    // pooling + MLP head
    tpn_pool<<<G, TPN_BLK, 0, stream>>>(hA, bat, N, Gf);
    tpn_mlp<<<(G * 64 + TPN_BLK - 1) / TPN_BLK, TPN_BLK, 0, stream>>>(Gf, lw1, lb1, lw2, lb2, out, G, C);
}

// Round 18
// 347.201 us; speedup vs baseline: 4.8701x; 1.0406x over previous
//
#include <hip/hip_runtime.h>
#include <hip/hip_fp16.h>
#include <math.h>

// ---------------------------------------------------------------------------
// TopoPoolNet: GCN(128->64) -> GCN(64->64) -> sigmoid score gate ->
//              per-graph max||mean pool -> MLP(128->64->2)
//
// Round-17: agg proved NOT bytes-bound (fp16 halved FETCH, time flat at
// ~117us, fetch rate only 1.4TB/s). Hypothesis: divergent-address processing
// rate. This round: 8 lanes x dwordx4 (16B) per edge row -> 8 addresses per
// row instead of 16; 8 edge slots per wave; pack loads halved too.
// All math fp32, activations fp16 (R16). Everything else unchanged.
// ---------------------------------------------------------------------------

#define TPN_BLK 256
#define P1_EPT  16                   // edges per thread in bin pass
#define P1_CHUNK (TPN_BLK * P1_EPT)  // 4096 edges per block
#define NB_MAX  512
#define BCAP    12288                // per-bin capacity (mean ~8184)

static __device__ __forceinline__ uint2 f4_to_h4(float4 v) {
    __half2 a = __floats2half2_rn(v.x, v.y);
    __half2 b = __floats2half2_rn(v.z, v.w);
    uint2 u;
    u.x = *reinterpret_cast<unsigned*>(&a);
    u.y = *reinterpret_cast<unsigned*>(&b);
    return u;
}

// ---- pass 1: block-level counting sort by bin (col>>8), coalesced out -----
__global__ __launch_bounds__(256)
void tpn_bin(const int* __restrict__ ei, const float* __restrict__ ew,
             int* __restrict__ binCur, uint2* __restrict__ binned,
             int E, int NB) {
    __shared__ uint2          sbuf[P1_CHUNK];      // 32 KB
    __shared__ unsigned short sbin[P1_CHUNK];      // 8 KB
    __shared__ int hist[NB_MAX];
    __shared__ int loff[NB_MAX];
    __shared__ int lrank[NB_MAX];
    __shared__ int gbase[NB_MAX];
    __shared__ int ssc[256];

    int tid = threadIdx.x;
    for (int b = tid; b < NB_MAX; b += 256) { hist[b] = 0; lrank[b] = 0; }
    __syncthreads();

    int base = blockIdx.x * P1_CHUNK;
    uint2 ed[P1_EPT];
    int   bn[P1_EPT];
    #pragma unroll
    for (int j = 0; j < P1_EPT; ++j) {
        int e = base + tid + j * 256;
        bn[j] = -1;
        if (e < E) {
            int r = ei[e], c = ei[E + e];
            bn[j] = c >> 8;
            ed[j] = make_uint2((unsigned)r | ((unsigned)(c & 255) << 17),
                               __float_as_uint(ew[e]));
            atomicAdd(&hist[bn[j]], 1);
        }
    }
    __syncthreads();
    {
        int b0 = 2 * tid, b1 = 2 * tid + 1;
        int h0 = hist[b0], h1 = hist[b1];
        int s = h0 + h1;
        ssc[tid] = s;
        __syncthreads();
        for (int st = 1; st < 256; st <<= 1) {
            int v = (tid >= st) ? ssc[tid - st] : 0;
            __syncthreads();
            ssc[tid] += v;
            __syncthreads();
        }
        int pre = ssc[tid] - s;
        loff[b0] = pre;
        loff[b1] = pre + h0;
    }
    __syncthreads();
    for (int b = tid; b < NB; b += 256) {
        int h = hist[b];
        if (h > 0) gbase[b] = atomicAdd(&binCur[b], h);
    }
    #pragma unroll
    for (int j = 0; j < P1_EPT; ++j) {
        if (bn[j] >= 0) {
            int p = loff[bn[j]] + atomicAdd(&lrank[bn[j]], 1);
            sbuf[p] = ed[j];
            sbin[p] = (unsigned short)bn[j];
        }
    }
    __syncthreads();
    int m = min(E - base, P1_CHUNK);
    for (int i = tid; i < m; i += 256) {
        uint2 u = sbuf[i];
        int b = sbin[i];
        int dst = gbase[b] + (i - loff[b]);
        if (dst < BCAP) binned[(size_t)b * BCAP + dst] = u;
    }
}

// ---- exclusive scan of bin counts (single block) ---------------------------
__global__ void tpn_binscan(const int* __restrict__ binCur, int* __restrict__ binOff,
                            int NB) {
    __shared__ int sh[NB_MAX];
    int t = threadIdx.x;
    int v = (t < NB) ? min(binCur[t], BCAP) : 0;
    sh[t] = v;
    __syncthreads();
    for (int st = 1; st < NB_MAX; st <<= 1) {
        int u = (t >= st) ? sh[t - st] : 0;
        __syncthreads();
        sh[t] += u;
        __syncthreads();
    }
    if (t < NB) binOff[t] = sh[t] - v;
}

// ---- pass 2: per-bin packed CSR build + dis --------------------------------
__global__ void tpn_build(const uint2* __restrict__ binned, const int* __restrict__ binCur,
                          const int* __restrict__ binOff, uint2* __restrict__ packed,
                          int* __restrict__ off, int* __restrict__ cnt,
                          float* __restrict__ dis, int N) {
    __shared__ int   lcnt[256];
    __shared__ int   loff[256];
    __shared__ int   lrank[256];
    __shared__ int   lincl[256];
    __shared__ float ldeg[256];
    int b = blockIdx.x, tid = threadIdx.x;
    int m = min(binCur[b], BCAP);
    const uint2* src = binned + (size_t)b * BCAP;
    lcnt[tid] = 0; lrank[tid] = 0; ldeg[tid] = 0.0f;
    __syncthreads();
    for (int i = tid; i < m; i += 256) {
        uint2 u = src[i];
        int ln = u.x >> 17;
        atomicAdd(&lcnt[ln], 1);
        atomicAdd(&ldeg[ln], __uint_as_float(u.y));
    }
    __syncthreads();
    lincl[tid] = lcnt[tid];
    __syncthreads();
    for (int st = 1; st < 256; st <<= 1) {
        int u = (tid >= st) ? lincl[tid - st] : 0;
        __syncthreads();
        lincl[tid] += u;
        __syncthreads();
    }
    int excl = lincl[tid] - lcnt[tid];
    loff[tid] = excl;
    int node = (b << 8) + tid;
    if (node < N) {
        off[node] = binOff[b] + excl;
        cnt[node] = lcnt[tid];
        float s = ldeg[tid];
        dis[node] = (s > 0.0f) ? rsqrtf(fmaxf(s, 1e-12f)) : 0.0f;
    }
    __syncthreads();
    int gbase = binOff[b];
    for (int i = tid; i < m; i += 256) {
        uint2 u = src[i];
        int ln = u.x >> 17;
        int rk = atomicAdd(&lrank[ln], 1);
        packed[gbase + loff[ln] + rk] = make_uint2(u.x & 0x1FFFF, u.y);
    }
}

// ---- tiled GEMM: Y[n,f] = fp16(dis[n] * sum_k X[n,k]*W[k,f]); 64x64 tile ---
__global__ __launch_bounds__(256, 4)
void tpn_gemm_t(const float* __restrict__ X, const float* __restrict__ W,
                const float* __restrict__ dis, __half* __restrict__ Y,
                int N, int K) {
    __shared__ float sX[64][68];
    __shared__ float sW[64][64];
    const int t  = threadIdx.x;
    const int r  = t >> 4;
    const int cc = t & 15;
    const int fg = t & 15;
    const int ng = t >> 4;
    const int nb = blockIdx.x * 64;

    float acc[4][4] = {{0.f}};

    for (int kc = 0; kc < K; kc += 64) {
        __syncthreads();
        #pragma unroll
        for (int p = 0; p < 4; ++p) {
            int n = nb + r + p * 16;
            int ns = (n < N) ? n : (N - 1);
            float4 v = *reinterpret_cast<const float4*>(X + (size_t)ns * K + kc + 4 * cc);
            *reinterpret_cast<float4*>(&sX[r + p * 16][4 * cc]) = v;
        }
        #pragma unroll
        for (int p = 0; p < 4; ++p) {
            int k = kc + r + p * 16;
            float4 v = *reinterpret_cast<const float4*>(W + (size_t)k * 64 + 4 * cc);
            *reinterpret_cast<float4*>(&sW[r + p * 16][4 * cc]) = v;
        }
        __syncthreads();
        #pragma unroll 4
        for (int k = 0; k < 64; ++k) {
            float4 wv = *reinterpret_cast<const float4*>(&sW[k][4 * fg]);
            float x0 = sX[4 * ng + 0][k];
            float x1 = sX[4 * ng + 1][k];
            float x2 = sX[4 * ng + 2][k];
            float x3 = sX[4 * ng + 3][k];
            acc[0][0] = fmaf(x0, wv.x, acc[0][0]);
            acc[0][1] = fmaf(x0, wv.y, acc[0][1]);
            acc[0][2] = fmaf(x0, wv.z, acc[0][2]);
            acc[0][3] = fmaf(x0, wv.w, acc[0][3]);
            acc[1][0] = fmaf(x1, wv.x, acc[1][0]);
            acc[1][1] = fmaf(x1, wv.y, acc[1][1]);
            acc[1][2] = fmaf(x1, wv.z, acc[1][2]);
            acc[1][3] = fmaf(x1, wv.w, acc[1][3]);
            acc[2][0] = fmaf(x2, wv.x, acc[2][0]);
            acc[2][1] = fmaf(x2, wv.y, acc[2][1]);
            acc[2][2] = fmaf(x2, wv.z, acc[2][2]);
            acc[2][3] = fmaf(x2, wv.w, acc[2][3]);
            acc[3][0] = fmaf(x3, wv.x, acc[3][0]);
            acc[3][1] = fmaf(x3, wv.y, acc[3][1]);
            acc[3][2] = fmaf(x3, wv.z, acc[3][2]);
            acc[3][3] = fmaf(x3, wv.w, acc[3][3]);
        }
    }
    #pragma unroll
    for (int i = 0; i < 4; ++i) {
        int n = nb + 4 * ng + i;
        if (n < N) {
            float d = dis[n];
            float4 v = make_float4(acc[i][0] * d, acc[i][1] * d,
                                   acc[i][2] * d, acc[i][3] * d);
            *reinterpret_cast<uint2*>(Y + (size_t)n * 64 + 4 * fg) = f4_to_h4(v);
        }
    }
}

// ---- aggregate: wave/node, 8 lanes x dwordx4 (16B) per edge row ------------
// 8 edge slots/wave, 2 unrolled passes -> 16 rows in flight, 8 addr/row.
// FUSE_W2: epilogue computes Hout_row = fp16(dis[n] * (relu_row @ W2)).
// FUSE_SCORE: sigmoid score gate (layer 2).
template <bool FUSE_SCORE, bool FUSE_W2>
__global__ __launch_bounds__(256)
void tpn_agg(const uint2* __restrict__ packed, const int* __restrict__ off,
             const int* __restrict__ cnt, const float* __restrict__ dis,
             const __half* __restrict__ Hin, const float* __restrict__ bias,
             const float* __restrict__ pw, const float* __restrict__ pb,
             const float* __restrict__ W2, __half* __restrict__ Hout, int N) {
    int wid = (blockIdx.x * blockDim.x + threadIdx.x) >> 6;
    int lane = threadIdx.x & 63;
    if (wid >= N) return;
    const int eg = lane >> 3;        // edge slot 0..7
    const int fb = (lane & 7) * 8;   // feature base: fb..fb+7 (8 fp16 = 16B)
    int start = off[wid], n = cnt[wid];
    const uint2* b = packed + start;
    const __half* hp = Hin + fb;
    float dc = dis[wid];

    float A0[8], A1[8];
    #pragma unroll
    for (int i = 0; i < 8; ++i) { A0[i] = 0.f; A1[i] = 0.f; }

    int j = 0;
    for (; j + 16 <= n; j += 16) {
        uint2 p0 = b[j + eg];
        uint2 p1 = b[j + 8 + eg];
        uint4 r0 = *reinterpret_cast<const uint4*>(hp + (size_t)p0.x * 64);
        uint4 r1 = *reinterpret_cast<const uint4*>(hp + (size_t)p1.x * 64);
        float w0 = __uint_as_float(p0.y);
        float w1 = __uint_as_float(p1.y);
        {
            float2 a = __half22float2(*reinterpret_cast<__half2*>(&r0.x));
            float2 c = __half22float2(*reinterpret_cast<__half2*>(&r0.y));
            float2 d = __half22float2(*reinterpret_cast<__half2*>(&r0.z));
            float2 e = __half22float2(*reinterpret_cast<__half2*>(&r0.w));
            A0[0] = fmaf(w0, a.x, A0[0]); A0[1] = fmaf(w0, a.y, A0[1]);
            A0[2] = fmaf(w0, c.x, A0[2]); A0[3] = fmaf(w0, c.y, A0[3]);
            A0[4] = fmaf(w0, d.x, A0[4]); A0[5] = fmaf(w0, d.y, A0[5]);
            A0[6] = fmaf(w0, e.x, A0[6]); A0[7] = fmaf(w0, e.y, A0[7]);
        }
        {
            float2 a = __half22float2(*reinterpret_cast<__half2*>(&r1.x));
            float2 c = __half22float2(*reinterpret_cast<__half2*>(&r1.y));
            float2 d = __half22float2(*reinterpret_cast<__half2*>(&r1.z));
            float2 e = __half22float2(*reinterpret_cast<__half2*>(&r1.w));
            A1[0] = fmaf(w1, a.x, A1[0]); A1[1] = fmaf(w1, a.y, A1[1]);
            A1[2] = fmaf(w1, c.x, A1[2]); A1[3] = fmaf(w1, c.y, A1[3]);
            A1[4] = fmaf(w1, d.x, A1[4]); A1[5] = fmaf(w1, d.y, A1[5]);
            A1[6] = fmaf(w1, e.x, A1[6]); A1[7] = fmaf(w1, e.y, A1[7]);
        }
    }
    for (; j < n; j += 8) {
        int idx = j + eg;
        uint2 p = (idx < n) ? b[idx] : make_uint2(0u, 0u);  // w=0 for pad lanes
        uint4 r = *reinterpret_cast<const uint4*>(hp + (size_t)p.x * 64);
        float w = __uint_as_float(p.y);
        float2 a = __half22float2(*reinterpret_cast<__half2*>(&r.x));
        float2 c = __half22float2(*reinterpret_cast<__half2*>(&r.y));
        float2 d = __half22float2(*reinterpret_cast<__half2*>(&r.z));
        float2 e = __half22float2(*reinterpret_cast<__half2*>(&r.w));
        A0[0] = fmaf(w, a.x, A0[0]); A0[1] = fmaf(w, a.y, A0[1]);
        A0[2] = fmaf(w, c.x, A0[2]); A0[3] = fmaf(w, c.y, A0[3]);
        A0[4] = fmaf(w, d.x, A0[4]); A0[5] = fmaf(w, d.y, A0[5]);
        A0[6] = fmaf(w, e.x, A0[6]); A0[7] = fmaf(w, e.y, A0[7]);
    }

    float h[8];
    #pragma unroll
    for (int i = 0; i < 8; ++i) {
        float a = A0[i] + A1[i];
        a += __shfl_xor(a, 8);
        a += __shfl_xor(a, 16);
        a += __shfl_xor(a, 32);
        h[i] = a;
    }
    const float4 bv0 = *reinterpret_cast<const float4*>(bias + fb);
    const float4 bv1 = *reinterpret_cast<const float4*>(bias + fb + 4);
    h[0] = fmaxf(fmaf(h[0], dc, bv0.x), 0.0f);
    h[1] = fmaxf(fmaf(h[1], dc, bv0.y), 0.0f);
    h[2] = fmaxf(fmaf(h[2], dc, bv0.z), 0.0f);
    h[3] = fmaxf(fmaf(h[3], dc, bv0.w), 0.0f);
    h[4] = fmaxf(fmaf(h[4], dc, bv1.x), 0.0f);
    h[5] = fmaxf(fmaf(h[5], dc, bv1.y), 0.0f);
    h[6] = fmaxf(fmaf(h[6], dc, bv1.z), 0.0f);
    h[7] = fmaxf(fmaf(h[7], dc, bv1.w), 0.0f);
    if (FUSE_SCORE) {
        const float4 pv0 = *reinterpret_cast<const float4*>(pw + fb);
        const float4 pv1 = *reinterpret_cast<const float4*>(pw + fb + 4);
        float t = h[0] * pv0.x + h[1] * pv0.y + h[2] * pv0.z + h[3] * pv0.w
                + h[4] * pv1.x + h[5] * pv1.y + h[6] * pv1.z + h[7] * pv1.w;
        #pragma unroll
        for (int m = 1; m <= 4; m <<= 1) t += __shfl_xor(t, m);  // 8-lane group
        float s = 1.0f / (1.0f + expf(-(t + pb[0])));
        #pragma unroll
        for (int i = 0; i < 8; ++i) h[i] *= s;
    }
    if (FUSE_W2) {
        // lane q (0..7) holds hB[8q..8q+7]; out[lane] = dis*sum_k hB[k]*W2[k][lane]
        float a2 = 0.0f;
        #pragma unroll
        for (int q = 0; q < 8; ++q) {
            #pragma unroll
            for (int i = 0; i < 8; ++i) {
                float bq = __shfl(h[i], q);
                a2 = fmaf(bq, W2[(8 * q + i) * 64 + lane], a2);
            }
        }
        Hout[(size_t)wid * 64 + lane] = __float2half(dc * a2);  // coalesced 2B/lane
    } else {
        if (eg == 0) {
            uint4 u;
            __half2 a = __floats2half2_rn(h[0], h[1]);
            __half2 c = __floats2half2_rn(h[2], h[3]);
            __half2 d = __floats2half2_rn(h[4], h[5]);
            __half2 e = __floats2half2_rn(h[6], h[7]);
            u.x = *reinterpret_cast<unsigned*>(&a);
            u.y = *reinterpret_cast<unsigned*>(&c);
            u.z = *reinterpret_cast<unsigned*>(&d);
            u.w = *reinterpret_cast<unsigned*>(&e);
            *reinterpret_cast<uint4*>(Hout + (size_t)wid * 64 + fb) = u;
        }
    }
}

// ---- per-graph max || mean pooling (batch sorted, fp16 input) --------------
__global__ void tpn_pool(const __half* __restrict__ Hs, const int* __restrict__ batch,
                         int N, float* __restrict__ Gf) {
    int g = blockIdx.x;
    int s, e;
    {
        int lo = 0, hi = N;
        while (lo < hi) { int mid = (lo + hi) >> 1; if (batch[mid] < g) lo = mid + 1; else hi = mid; }
        s = lo;
        lo = 0; hi = N;
        while (lo < hi) { int mid = (lo + hi) >> 1; if (batch[mid] < g + 1) lo = mid + 1; else hi = mid; }
        e = lo;
    }
    int lane = threadIdx.x & 63;
    int w = threadIdx.x >> 6;  // 0..3
    float mx = -3.4e38f, sm = 0.0f;
    for (int i = s + w; i < e; i += 4) {
        float v = __half2float(Hs[(size_t)i * 64 + lane]);
        mx = fmaxf(mx, v);
        sm += v;
    }
    __shared__ float shm[4][64], shs[4][64];
    shm[w][lane] = mx; shs[w][lane] = sm;
    __syncthreads();
    if (w == 0) {
        mx = fmaxf(fmaxf(shm[0][lane], shm[1][lane]), fmaxf(shm[2][lane], shm[3][lane]));
        sm = shs[0][lane] + shs[1][lane] + shs[2][lane] + shs[3][lane];
        float c = (float)(e - s);
        float inv = 1.0f / fmaxf(c, 1.0f);
        Gf[g * 128 + lane]      = mx;
        Gf[g * 128 + 64 + lane] = sm * inv;
    }
}

// ---- final MLP: out = relu(G @ lw1 + lb1) @ lw2 + lb2 ----------------------
__global__ void tpn_mlp(const float* __restrict__ Gf, const float* __restrict__ lw1,
                        const float* __restrict__ lb1, const float* __restrict__ lw2,
                        const float* __restrict__ lb2, float* __restrict__ out,
                        int G, int C) {
    int wid = (blockIdx.x * blockDim.x + threadIdx.x) >> 6;
    int lane = threadIdx.x & 63;
    if (wid >= G) return;
    const float* gr = Gf + (size_t)wid * 128;
    float acc = lb1[lane];
    for (int k = 0; k < 128; k += 4) {
        float4 gv = *reinterpret_cast<const float4*>(gr + k);
        acc = fmaf(gv.x, lw1[(k + 0) * 64 + lane], acc);
        acc = fmaf(gv.y, lw1[(k + 1) * 64 + lane], acc);
        acc = fmaf(gv.z, lw1[(k + 2) * 64 + lane], acc);
        acc = fmaf(gv.w, lw1[(k + 3) * 64 + lane], acc);
    }
    float t = fmaxf(acc, 0.0f);
    for (int c = 0; c < C; ++c) {
        float v = t * lw2[lane * C + c];
        #pragma unroll
        for (int m = 32; m > 0; m >>= 1) v += __shfl_xor(v, m);
        if (lane == 0) out[wid * C + c] = v + lb2[c];
    }
}

// ---------------------------------------------------------------------------
extern "C" void kernel_launch(void* const* d_in, const int* in_sizes, int n_in,
                              void* d_out, int out_size, void* d_ws, size_t ws_size,
                              hipStream_t stream) {
    const float* x   = (const float*)d_in[0];
    const int*   ei  = (const int*)  d_in[1];
    const float* ew  = (const float*)d_in[2];
    const int*   bat = (const int*)  d_in[3];
    const float* W1  = (const float*)d_in[5];
    const float* b1  = (const float*)d_in[6];
    const float* W2  = (const float*)d_in[7];
    const float* b2  = (const float*)d_in[8];
    const float* pw  = (const float*)d_in[9];
    const float* pb  = (const float*)d_in[10];
    const float* lw1 = (const float*)d_in[11];
    const float* lb1 = (const float*)d_in[12];
    const float* lw2 = (const float*)d_in[13];
    const float* lb2 = (const float*)d_in[14];
    float* out = (float*)d_out;

    const int N  = in_sizes[3];
    const int E  = in_sizes[2];
    const int IN = in_sizes[0] / N;   // 128
    const int C  = in_sizes[14];      // 2
    const int G  = out_size / C;      // 128
    const int NB = (N + 255) >> 8;    // bins of 256 nodes

    // ---- workspace layout ----
    char* ws = (char*)d_ws;
    size_t o = 0;
    auto alloc = [&](size_t bytes) { void* p = ws + o; o = (o + bytes + 255) & ~(size_t)255; return p; };
    int*   off    = (int*)  alloc((size_t)N * 4);
    int*   cnt    = (int*)  alloc((size_t)N * 4);
    float* dis    = (float*)alloc((size_t)N * 4);
    int*   binCur = (int*)  alloc((size_t)NB_MAX * 4);
    int*   binOff = (int*)  alloc((size_t)NB_MAX * 4);
    float* Gf     = (float*)alloc((size_t)G * 128 * 4);
    uint2* packed = (uint2*)alloc((size_t)E * 8);
    // shared region: binned (NB*BCAP*8 = 38.4MB) overlays hA+hB (25.6MB);
    // binned dead after tpn_build.
    size_t binned_bytes = (size_t)NB * BCAP * 8;
    size_t act_bytes    = (size_t)N * 64 * 2 * 2;
    char*  region = (char*)alloc(binned_bytes > act_bytes ? binned_bytes : act_bytes);
    uint2* binned = (uint2*)region;
    __half* hA = (__half*)region;
    __half* hB = (__half*)(region + (size_t)N * 64 * 2);
    (void)n_in; (void)ws_size;

    (void)hipMemsetAsync(binCur, 0, (size_t)NB_MAX * 4, stream);

    const int p1b   = (E + P1_CHUNK - 1) / P1_CHUNK;
    const int ggrid = (N + 63) / 64;                        // gemm tiles
    const int agrid = (N * 64 + TPN_BLK - 1) / TPN_BLK;     // wave per node

    // CSR build: bin (LDS sort, coalesced) -> scan -> build
    tpn_bin<<<p1b, TPN_BLK, 0, stream>>>(ei, ew, binCur, binned, E, NB);
    tpn_binscan<<<1, NB_MAX, 0, stream>>>(binCur, binOff, NB);
    tpn_build<<<NB, 256, 0, stream>>>(binned, binCur, binOff, packed, off, cnt, dis, N);

    // layer 1 (+fused gemm2): hA = fp16(dis*(x@W1));
    //                         hB = fp16(dis*(relu(dis*agg(hA)+b1)@W2))
    tpn_gemm_t<<<ggrid, 256, 0, stream>>>(x, W1, dis, hA, N, IN);
    tpn_agg<false, true><<<agrid, TPN_BLK, 0, stream>>>(packed, off, cnt, dis, hA,
                                                        b1, pw, pb, W2, hB, N);

    // layer 2: hA = fp16(score-gated relu(dis*agg(hB) + b2))
    tpn_agg<true, false><<<agrid, TPN_BLK, 0, stream>>>(packed, off, cnt, dis, hB,
                                                        b2, pw, pb, W2, hA, N);

    // pooling + MLP head
    tpn_pool<<<G, TPN_BLK, 0, stream>>>(hA, bat, N, Gf);
    tpn_mlp<<<(G * 64 + TPN_BLK - 1) / TPN_BLK, TPN_BLK, 0, stream>>>(Gf, lw1, lb1, lw2, lb2, out, G, C);
}